// Round 1
// baseline (1437.781 us; speedup 1.0000x reference)
//
#include <hip/hip_runtime.h>
#include <math.h>

#define HRV 16
#define WRV 1024
#define NPIX 16384
#define NBEV 48400
#define BSZ 2

struct RVConsts {
  float steps[16];
  float means[16];
  float az_step_f;
  float pad_;
  double step_d;
  double az0;
  double az_half;
};

__device__ __forceinline__ float geluf(float x) {
  return 0.5f * x * (1.0f + erff(x * 0.70710678118654752440f));
}
__device__ __forceinline__ float sigmoidf_(float x) {
  return 1.0f / (1.0f + expf(-x));
}
__device__ __forceinline__ float softplusf_(float x) {
  return fmaxf(x, 0.0f) + log1pf(expf(-fabsf(x)));
}
__device__ __forceinline__ float azimf(int w, double step_d, double az0, double az_half) {
  double az = (double)w * step_d + az0;
  az += az_half;
  return (float)az;
}

// ---------------- K1: range-head conv1 (67->128) + Q0 conv (64->128) ----------------
__global__ __launch_bounds__(256) void k_rh1_q0(
    const float* __restrict__ x_rv,
    const float* __restrict__ rh_w1, const float* __restrict__ rh_b1,
    const float* __restrict__ w_q, const float* __restrict__ b_q,
    float* __restrict__ t1, float* __restrict__ q0, RVConsts C) {
  int b = blockIdx.y;
  int n0 = blockIdx.x * 16;
  int tid = threadIdx.x;
  __shared__ float xin[16][68];
  const float* src = x_rv + ((size_t)b * NPIX + n0) * 64;
  for (int i = tid; i < 16 * 64; i += 256) xin[i >> 6][i & 63] = src[i];
  if (tid < 16) {
    int n = n0 + tid;
    int h = n >> 10, w = n & 1023;
    float E = C.means[h];
    float A = azimf(w, C.step_d, C.az0, C.az_half);
    float ce = cosf(E);
    xin[tid][64] = ce * cosf(A);
    xin[tid][65] = ce * sinf(A);
    xin[tid][66] = sinf(E);
  }
  __syncthreads();
  int p = tid >> 4, co = tid & 15;
  float acc[8], accq[8];
#pragma unroll
  for (int j = 0; j < 8; j++) { acc[j] = rh_b1[co + 16 * j]; accq[j] = b_q[co + 16 * j]; }
  for (int c = 0; c < 67; c++) {
    float xv = xin[p][c];
#pragma unroll
    for (int j = 0; j < 8; j++) acc[j] += rh_w1[(size_t)(co + 16 * j) * 67 + c] * xv;
  }
  for (int c = 0; c < 64; c++) {
    float xv = xin[p][c];
#pragma unroll
    for (int j = 0; j < 8; j++) accq[j] += w_q[(size_t)(co + 16 * j) * 64 + c] * xv;
  }
  size_t base = ((size_t)b * NPIX + n0 + p) * 128;
#pragma unroll
  for (int j = 0; j < 8; j++) {
    t1[base + co + 16 * j] = acc[j];
    q0[base + co + 16 * j] = accq[j];
  }
}

// ---------------- GroupNorm partial sums (deterministic 2-stage) ----------------
template <int CCH, int CGRP>
__global__ __launch_bounds__(256) void k_gnsum(const float* __restrict__ src,
                                               float* __restrict__ sums) {
  int chunk = blockIdx.x;  // 16 chunks
  int g = blockIdx.y;      // 8 groups
  int b = blockIdx.z;      // B
  const int npx = NPIX / 16;
  int n0 = chunk * npx;
  int tid = threadIdx.x;
  float s = 0.f, ss = 0.f;
  const float* base = src + (size_t)b * NPIX * CCH + (size_t)g * CGRP;
  const int total = npx * CGRP;
  for (int i = tid; i < total; i += 256) {
    int n = i / CGRP;
    int cc = i % CGRP;
    float x = base[(size_t)(n0 + n) * CCH + cc];
    s += x; ss += x * x;
  }
#pragma unroll
  for (int o2 = 32; o2 > 0; o2 >>= 1) { s += __shfl_down(s, o2); ss += __shfl_down(ss, o2); }
  __shared__ float wsum[4][2];
  if ((tid & 63) == 0) { wsum[tid >> 6][0] = s; wsum[tid >> 6][1] = ss; }
  __syncthreads();
  if (tid == 0) {
    float S = wsum[0][0] + wsum[1][0] + wsum[2][0] + wsum[3][0];
    float SS = wsum[0][1] + wsum[1][1] + wsum[2][1] + wsum[3][1];
    sums[((b * 8 + g) * 16 + chunk) * 2 + 0] = S;
    sums[((b * 8 + g) * 16 + chunk) * 2 + 1] = SS;
  }
}

__global__ void k_gnfin(const float* __restrict__ sums, float* __restrict__ stats, float invN) {
  int i = threadIdx.x;
  if (i >= 16) return;
  float S = 0.f, SS = 0.f;
  for (int ch = 0; ch < 16; ch++) { S += sums[(i * 16 + ch) * 2]; SS += sums[(i * 16 + ch) * 2 + 1]; }
  float m = S * invN;
  float var = SS * invN - m * m;
  stats[i * 2] = m;
  stats[i * 2 + 1] = rsqrtf(var + 1e-5f);
}

// ---------------- K3: apply GN1 + GELU ----------------
__global__ __launch_bounds__(256) void k_gn1_gelu(
    const float* __restrict__ t1, const float* __restrict__ stats1,
    const float* __restrict__ g1, const float* __restrict__ bt1, float* __restrict__ h1) {
  size_t i = (size_t)blockIdx.x * 256 + threadIdx.x;
  int c = (int)(i & 127);
  int bidx = (int)(i >> 21);  // NPIX*128 = 2^21
  int g = c >> 4;
  float m = stats1[(bidx * 8 + g) * 2], is = stats1[(bidx * 8 + g) * 2 + 1];
  float x = (t1[i] - m) * is * g1[c] + bt1[c];
  h1[i] = geluf(x);
}

// ---------------- K4: 3x3 conv with circular pad (128 -> 64) ----------------
__global__ __launch_bounds__(256) void k_conv3(const float* __restrict__ h1,
                                               const float* __restrict__ w2,
                                               float* __restrict__ t2) {
  int b = blockIdx.y;
  int n0 = blockIdx.x * 16;
  int h = n0 >> 10;
  int w0 = n0 & 1023;
  int tid = threadIdx.x;
  __shared__ float tile[3][128][20];  // [row][channel][w-window(18 used)]
  for (int i = tid; i < 3 * 18 * 128; i += 256) {
    int r = i / 2304;
    int rem = i - r * 2304;
    int ww = rem >> 7;
    int c = rem & 127;
    int hh = (h + r - 1 + HRV) & (HRV - 1);
    int wc = (w0 + ww - 1 + WRV) & (WRV - 1);
    tile[r][c][ww] = h1[((size_t)b * NPIX + hh * WRV + wc) * 128 + c];
  }
  __syncthreads();
  int o = tid & 63, cq = tid >> 6;  // 64 outs x 4 c-quarters
  float acc[16];
#pragma unroll
  for (int px = 0; px < 16; px++) acc[px] = 0.0f;
  for (int cc = 0; cc < 32; cc++) {
    int c = cq * 32 + cc;
#pragma unroll
    for (int ky = 0; ky < 3; ky++) {
      const float4* row4 = (const float4*)&tile[ky][c][0];
      float4 a0 = row4[0], a1 = row4[1], a2 = row4[2], a3 = row4[3], a4 = row4[4];
      float win[20] = {a0.x, a0.y, a0.z, a0.w, a1.x, a1.y, a1.z, a1.w,
                       a2.x, a2.y, a2.z, a2.w, a3.x, a3.y, a3.z, a3.w,
                       a4.x, a4.y, a4.z, a4.w};
      const float* wp = w2 + ((size_t)(o * 128 + c) * 3 + ky) * 3;
      float wv0 = wp[0], wv1 = wp[1], wv2 = wp[2];
#pragma unroll
      for (int px = 0; px < 16; px++)
        acc[px] += wv0 * win[px] + wv1 * win[px + 1] + wv2 * win[px + 2];
    }
  }
  __syncthreads();
  float* psum = &tile[0][0][0];  // reuse LDS: [cq][px][o] = 4*16*64
#pragma unroll
  for (int px = 0; px < 16; px++) psum[(cq * 16 + px) * 64 + o] = acc[px];
  __syncthreads();
  for (int j = 0; j < 4; j++) {
    int px = j * 4 + cq;
    float s = psum[(0 * 16 + px) * 64 + o] + psum[(1 * 16 + px) * 64 + o] +
              psum[(2 * 16 + px) * 64 + o] + psum[(3 * 16 + px) * 64 + o];
    t2[((size_t)b * NPIX + n0 + px) * 64 + o] = s;
  }
}

// ---------------- K6: GN2+GELU -> head(4) -> params(sd,se,sa, ref[5][2]) + KL ----------------
__global__ __launch_bounds__(256) void k_head(
    const float* __restrict__ t2, const float* __restrict__ stats2,
    const float* __restrict__ g2, const float* __restrict__ bt2,
    const float* __restrict__ rh_w3, const float* __restrict__ rh_b3,
    const float* __restrict__ l2e, float* __restrict__ params,
    float* __restrict__ klpart, RVConsts C) {
  int b = blockIdx.y;
  int n = blockIdx.x * 256 + threadIdx.x;
  int h = n >> 10, w = n & 1023;
  const float* t = t2 + ((size_t)b * NPIX + n) * 64;
  float hd0 = rh_b3[0], hd1 = rh_b3[1], hd2 = rh_b3[2], hd3 = rh_b3[3];
  for (int c = 0; c < 64; c++) {
    int g = c >> 3;
    float m = stats2[(b * 8 + g) * 2], is = stats2[(b * 8 + g) * 2 + 1];
    float xv = geluf((t[c] - m) * is * g2[c] + bt2[c]);
    hd0 += rh_w3[c] * xv;
    hd1 += rh_w3[64 + c] * xv;
    hd2 += rh_w3[128 + c] * xv;
    hd3 += rh_w3[192 + c] * xv;
  }
  float mu = sigmoidf_(hd0) * 55.0f;
  float sd = softplusf_(hd1) + 1e-3f;
  float stepw = C.steps[w & 15];
  float se = sigmoidf_(hd2) * stepw + 1e-3f;
  float sa = sigmoidf_(hd3) * C.az_step_f + 1e-3f;
  float E0 = C.means[h];
  float A0 = azimf(w, C.step_d, C.az0, C.az_half);
  float* P = params + ((size_t)b * NPIX + n) * 16;
  P[0] = sd; P[1] = se; P[2] = sa;
  float M00 = l2e[0], M01 = l2e[1], M10 = l2e[4], M11 = l2e[5];
  float M20 = l2e[8], M21 = l2e[9], M30 = l2e[12], M31 = l2e[13];
#pragma unroll
  for (int k = 0; k < 5; k++) {
    float off = -0.6f + 0.3f * (float)k;
    float d = mu + sd * off;
    float E = E0 + se * off;
    float A = A0 + sa * off;
    float ce = cosf(E);
    float xl = d * ce * cosf(A), yl = d * ce * sinf(A), zl = d * sinf(E);
    float px = xl * M00 + yl * M10 + zl * M20 + M30;
    float py = xl * M01 + yl * M11 + zl * M21 + M31;
    P[3 + 2 * k] = sigmoidf_(4.0f * ((px + 55.0f) * (1.0f / 110.0f) - 0.5f));
    P[4 + 2 * k] = sigmoidf_(4.0f * ((py + 55.0f) * (1.0f / 110.0f) - 0.5f));
  }
  float mu_n = mu * (1.0f / 55.0f);
  float sr = fmaxf(sd, 1e-6f);
  float saz = sa / C.az_step_f;
  float sel = se / stepw;
  float L = 0.5f * (mu_n * mu_n + sr * sr - logf(sr * sr) - 1.0f) +
            0.5f * (saz * saz - logf(saz * saz) - 1.0f) +
            0.5f * (sel * sel - logf(sel * sel) - 1.0f);
#pragma unroll
  for (int o2 = 32; o2 > 0; o2 >>= 1) L += __shfl_down(L, o2);
  __shared__ float wsum[4];
  if ((threadIdx.x & 63) == 0) wsum[threadIdx.x >> 6] = L;
  __syncthreads();
  if (threadIdx.x == 0)
    klpart[blockIdx.y * 64 + blockIdx.x] = wsum[0] + wsum[1] + wsum[2] + wsum[3];
}

// ---------------- K7: query MLP: concat(Q0, sig_feat) -> 128 -> gelu -> 128 ----------------
__global__ __launch_bounds__(256) void k_query(
    const float* __restrict__ q0, const float* __restrict__ params,
    const float* __restrict__ qs_w1, const float* __restrict__ qs_b1,
    const float* __restrict__ qs_w2, const float* __restrict__ qs_b2,
    float* __restrict__ query) {
  int b = blockIdx.y;
  int n0 = blockIdx.x * 16;
  int tid = threadIdx.x;
  __shared__ float qin[16][136];
  __shared__ float hq[16][129];
  for (int i = tid; i < 16 * 128; i += 256) {
    int p = i >> 7, c = i & 127;
    qin[p][c] = q0[((size_t)b * NPIX + n0 + p) * 128 + c];
  }
  if (tid < 16) {
    const float* P = params + ((size_t)b * NPIX + n0 + tid) * 16;
    float sd = P[0], se = P[1], sa = P[2];
    qin[tid][128] = sd; qin[tid][129] = se; qin[tid][130] = sa;
    qin[tid][131] = 1.0f / (sd + 1e-6f);
    qin[tid][132] = 1.0f / (se + 1e-6f);
    qin[tid][133] = 1.0f / (sa + 1e-6f);
  }
  __syncthreads();
  int p = tid >> 4, co = tid & 15;
  float acc[8];
#pragma unroll
  for (int j = 0; j < 8; j++) acc[j] = qs_b1[co + 16 * j];
  for (int c = 0; c < 134; c++) {
    float xv = qin[p][c];
#pragma unroll
    for (int j = 0; j < 8; j++) acc[j] += qs_w1[(size_t)(co + 16 * j) * 134 + c] * xv;
  }
#pragma unroll
  for (int j = 0; j < 8; j++) hq[p][co + 16 * j] = geluf(acc[j]);
  __syncthreads();
#pragma unroll
  for (int j = 0; j < 8; j++) acc[j] = qs_b2[co + 16 * j];
  for (int c = 0; c < 128; c++) {
    float xv = hq[p][c];
#pragma unroll
    for (int j = 0; j < 8; j++) acc[j] += qs_w2[(size_t)(co + 16 * j) * 128 + c] * xv;
  }
  size_t base = ((size_t)b * NPIX + n0 + p) * 128;
#pragma unroll
  for (int j = 0; j < 8; j++) query[base + co + 16 * j] = acc[j];
}

// ---------------- K8: fold value path: Wvv = val_w @ w_v ; bvv = val_w@b_v + val_b ----------------
__global__ __launch_bounds__(256) void k_wvv(
    const float* __restrict__ val_w, const float* __restrict__ w_v,
    const float* __restrict__ b_v, const float* __restrict__ val_b,
    float* __restrict__ Wvv, float* __restrict__ bvv) {
  int idx = blockIdx.x * 256 + threadIdx.x;
  int o = idx >> 7, c = idx & 127;
  float acc = 0.0f;
  for (int m = 0; m < 128; m++) acc += val_w[o * 128 + m] * w_v[m * 128 + c];
  Wvv[idx] = acc;
  if (idx < 128) {
    float a2 = val_b[idx];
    for (int m = 0; m < 128; m++) a2 += val_w[idx * 128 + m] * b_v[m];
    bvv[idx] = a2;
  }
}

// ---------------- K9: v[b,p,128] = Wvv @ bev[b,:,p] + bvv ----------------
__global__ __launch_bounds__(256) void k_value(
    const float* __restrict__ bev, const float* __restrict__ Wvv,
    const float* __restrict__ bvv, float* __restrict__ v) {
  int b = blockIdx.y;
  int p0 = blockIdx.x * 64;
  int tid = threadIdx.x;
  __shared__ float bt[128][64];
  int npx = NBEV - p0; if (npx > 64) npx = 64;
  for (int i = tid; i < 128 * 64; i += 256) {
    int c = i >> 6, pp = i & 63;
    bt[c][pp] = (pp < npx) ? bev[(size_t)(b * 128 + c) * NBEV + p0 + pp] : 0.0f;
  }
  __syncthreads();
  int ob = (tid & 31) * 4;
  int pxg = tid >> 5;  // 0..7
  float acc[4][8];
#pragma unroll
  for (int j = 0; j < 4; j++) {
    float bz = bvv[ob + j];
#pragma unroll
    for (int i = 0; i < 8; i++) acc[j][i] = bz;
  }
  for (int c = 0; c < 128; c++) {
    const float4* row = (const float4*)&bt[c][pxg * 8];
    float4 r0 = row[0], r1 = row[1];
    float pxv[8] = {r0.x, r0.y, r0.z, r0.w, r1.x, r1.y, r1.z, r1.w};
#pragma unroll
    for (int j = 0; j < 4; j++) {
      float wv = Wvv[(size_t)(ob + j) * 128 + c];
#pragma unroll
      for (int i = 0; i < 8; i++) acc[j][i] += wv * pxv[i];
    }
  }
  for (int i = 0; i < 8; i++) {
    int pp = pxg * 8 + i;
    if (pp < npx) {
      float4 st = {acc[0][i], acc[1][i], acc[2][i], acc[3][i]};
      *(float4*)(v + ((size_t)b * NBEV + p0 + pp) * 128 + ob) = st;
    }
  }
}

// ---------------- K10: MSDA (proj 480, softmax20, 160 bilinear gathers, out proj + residual) ----------------
__global__ __launch_bounds__(256) void k_msda(
    const float* __restrict__ query, const float* __restrict__ params,
    const float* __restrict__ off_w, const float* __restrict__ off_b,
    const float* __restrict__ aw_w, const float* __restrict__ aw_b,
    const float* __restrict__ v, const float* __restrict__ out_w,
    const float* __restrict__ out_b, float* __restrict__ ymsda) {
  int b = blockIdx.y;
  int n0 = blockIdx.x * 16;
  int tid = threadIdx.x;
  __shared__ float qt[16][132];
  __shared__ float offb[16][321];
  __shared__ float logb[16][161];
  __shared__ float outb[16][129];
  for (int i = tid; i < 16 * 128; i += 256) {
    int p = i >> 7, c = i & 127;
    qt[p][c] = query[((size_t)b * NPIX + n0 + p) * 128 + c];
  }
  __syncthreads();
  // 480 projection rows (320 offsets + 160 attn logits) x 16 pixels
  for (int rr = tid; rr < 480; rr += 256) {
    const float* wrow = (rr < 320) ? (off_w + (size_t)rr * 128) : (aw_w + (size_t)(rr - 320) * 128);
    float bias = (rr < 320) ? off_b[rr] : aw_b[rr - 320];
    float acc[16];
#pragma unroll
    for (int p = 0; p < 16; p++) acc[p] = bias;
    for (int c = 0; c < 128; c += 4) {
      float4 w4 = *(const float4*)(wrow + c);
#pragma unroll
      for (int p = 0; p < 16; p++) {
        float4 q4 = *(const float4*)&qt[p][c];
        acc[p] += w4.x * q4.x + w4.y * q4.y + w4.z * q4.z + w4.w * q4.w;
      }
    }
    if (rr < 320) {
#pragma unroll
      for (int p = 0; p < 16; p++) offb[p][rr] = acc[p];
    } else {
#pragma unroll
      for (int p = 0; p < 16; p++) logb[p][rr - 320] = acc[p];
    }
  }
  __syncthreads();
  if (tid < 128) {  // softmax over 20 per (pixel, head)
    int p = tid >> 3, hh = tid & 7;
    float* L = &logb[p][hh * 20];
    float mx = L[0];
    for (int i = 1; i < 20; i++) mx = fmaxf(mx, L[i]);
    float s = 0.0f;
    for (int i = 0; i < 20; i++) { float e = expf(L[i] - mx); L[i] = e; s += e; }
    float r = 1.0f / s;
    for (int i = 0; i < 20; i++) L[i] *= r;
  }
  __syncthreads();
  {  // sampling: thread = (pixel, head, half-of-20-points)
    int p = tid >> 4;
    int hh = (tid >> 1) & 7;
    int half = tid & 1;
    const float* P = params + ((size_t)b * NPIX + n0 + p) * 16;
    const float* vb = v + (size_t)b * NBEV * 128 + hh * 16;
    float acc[16];
#pragma unroll
    for (int d = 0; d < 16; d++) acc[d] = 0.0f;
    for (int t = 0; t < 10; t++) {
      int kp = half * 10 + t;
      int k = kp >> 2, pp = kp & 3;
      float lx = P[3 + 2 * k] + offb[p][hh * 40 + k * 8 + pp * 2 + 0] / 220.0f;
      float ly = P[4 + 2 * k] + offb[p][hh * 40 + k * 8 + pp * 2 + 1] / 220.0f;
      float a = logb[p][hh * 20 + kp];
      float X = lx * 220.0f - 0.5f;
      float Y = ly * 220.0f - 0.5f;
      float xf = floorf(X), yf = floorf(Y);
      float wx = X - xf, wy = Y - yf;
      int x0 = (int)xf, y0 = (int)yf;
#pragma unroll
      for (int dy = 0; dy < 2; dy++) {
        int yi = y0 + dy;
        if (yi < 0 || yi >= 220) continue;
        float wyv = dy ? wy : (1.0f - wy);
#pragma unroll
        for (int dx = 0; dx < 2; dx++) {
          int xi = x0 + dx;
          if (xi < 0 || xi >= 220) continue;
          float wgt = a * wyv * (dx ? wx : (1.0f - wx));
          const float4* s4 = (const float4*)(vb + (size_t)(yi * 220 + xi) * 128);
#pragma unroll
          for (int q4i = 0; q4i < 4; q4i++) {
            float4 vv = s4[q4i];
            acc[4 * q4i + 0] += wgt * vv.x;
            acc[4 * q4i + 1] += wgt * vv.y;
            acc[4 * q4i + 2] += wgt * vv.z;
            acc[4 * q4i + 3] += wgt * vv.w;
          }
        }
      }
    }
    if (half == 0) {
#pragma unroll
      for (int d = 0; d < 16; d++) outb[p][hh * 16 + d] = acc[d];
    }
    __syncthreads();
    if (half == 1) {
#pragma unroll
      for (int d = 0; d < 16; d++) outb[p][hh * 16 + d] += acc[d];
    }
    __syncthreads();
  }
  {  // out projection + residual
    int p = tid >> 4, co = tid & 15;
    float acc[8];
#pragma unroll
    for (int j = 0; j < 8; j++) acc[j] = out_b[co + 16 * j];
    for (int c = 0; c < 128; c++) {
      float xv = outb[p][c];
#pragma unroll
      for (int j = 0; j < 8; j++) acc[j] += out_w[(size_t)(co + 16 * j) * 128 + c] * xv;
    }
    size_t qb = ((size_t)b * NPIX + n0 + p) * 128;
#pragma unroll
    for (int j = 0; j < 8; j++) ymsda[qb + co + 16 * j] = acc[j] + qt[p][co + 16 * j];
  }
}

// ---------------- K11: final conv1x1 (w_o) with NCHW-ordered output ----------------
__global__ __launch_bounds__(256) void k_final(
    const float* __restrict__ ymsda, const float* __restrict__ w_o,
    const float* __restrict__ b_o, float* __restrict__ out) {
  int b = blockIdx.y;
  int n0 = blockIdx.x * 64;
  int tid = threadIdx.x;
  __shared__ float yt[128][68];
  for (int i = tid; i < 64 * 128; i += 256) {
    int p = i >> 7, c = i & 127;
    yt[c][p] = ymsda[((size_t)b * NPIX + n0 + p) * 128 + c];
  }
  __syncthreads();
  int ob = (tid & 31) * 4;
  int pxg = tid >> 5;
  float acc[4][8];
#pragma unroll
  for (int j = 0; j < 4; j++) {
    float bz = b_o[ob + j];
#pragma unroll
    for (int i = 0; i < 8; i++) acc[j][i] = bz;
  }
  for (int c = 0; c < 128; c++) {
    const float4* row = (const float4*)&yt[c][pxg * 8];
    float4 r0 = row[0], r1 = row[1];
    float pxv[8] = {r0.x, r0.y, r0.z, r0.w, r1.x, r1.y, r1.z, r1.w};
#pragma unroll
    for (int j = 0; j < 4; j++) {
      float wv = w_o[(size_t)(ob + j) * 128 + c];
#pragma unroll
      for (int i = 0; i < 8; i++) acc[j][i] += wv * pxv[i];
    }
  }
#pragma unroll
  for (int j = 0; j < 4; j++) {
    float* dst = out + (size_t)(b * 128 + ob + j) * NPIX + n0 + pxg * 8;
    float4 s0 = {acc[j][0], acc[j][1], acc[j][2], acc[j][3]};
    float4 s1 = {acc[j][4], acc[j][5], acc[j][6], acc[j][7]};
    *(float4*)dst = s0;
    *(float4*)(dst + 4) = s1;
  }
}

__global__ void k_klfin(const float* __restrict__ klpart, float* __restrict__ out) {
  if (threadIdx.x == 0) {
    float s = 0.0f;
    for (int i = 0; i < 128; i++) s += klpart[i];
    out[(size_t)BSZ * 128 * NPIX] = 1e-4f * (s / 32768.0f);
  }
}

// ---------------- host ----------------
static RVConsts make_consts() {
  static const float ELEV[32] = {
      -30.67f, -29.33f, -28.0f, -26.66f, -25.33f, -24.0f, -22.67f, -21.33f,
      -20.0f,  -18.67f, -17.33f, -16.0f, -14.67f, -13.33f, -12.0f, -10.67f,
      -9.33f,  -8.0f,   -6.66f,  -5.33f, -4.0f,   -2.67f,  -1.33f, 0.0f,
      1.33f,   2.67f,   4.0f,    5.33f,  6.67f,   8.0f,    9.33f,  10.67f};
  RVConsts C;
  const float d2r = 0.017453292519943295f;
  for (int r = 0; r < 16; r++) {
    float a = ELEV[31 - 2 * r], b = ELEV[30 - 2 * r];
    float mx = fmaxf(a, b), mn = fminf(a, b);
    C.steps[r] = (mx - mn) * d2r;
    C.means[r] = ((a + b) * 0.5f) * d2r;
  }
  const double PI_D = 3.14159265358979323846;
  double step_d = (PI_D - (-PI_D)) / 1024.0;
  double az0 = -PI_D;
  double az1 = az0 + step_d;
  double az_step_d = az1 - az0;
  C.az_step_f = (float)az_step_d;
  C.pad_ = 0.0f;
  C.step_d = step_d;
  C.az0 = az0;
  C.az_half = az_step_d * 0.5;
  return C;
}

extern "C" void kernel_launch(void* const* d_in, const int* in_sizes, int n_in,
                              void* d_out, int out_size, void* d_ws, size_t ws_size,
                              hipStream_t stream) {
  const float* x_rv = (const float*)d_in[0];
  const float* bev = (const float*)d_in[1];
  const float* l2e = (const float*)d_in[2];
  const float* w_q = (const float*)d_in[3];
  const float* b_q = (const float*)d_in[4];
  const float* w_v = (const float*)d_in[5];
  const float* b_v = (const float*)d_in[6];
  const float* w_o = (const float*)d_in[7];
  const float* b_o = (const float*)d_in[8];
  const float* qs_w1 = (const float*)d_in[9];
  const float* qs_b1 = (const float*)d_in[10];
  const float* qs_w2 = (const float*)d_in[11];
  const float* qs_b2 = (const float*)d_in[12];
  const float* rh_w1 = (const float*)d_in[13];
  const float* rh_b1 = (const float*)d_in[14];
  const float* rh_g1 = (const float*)d_in[15];
  const float* rh_bt1 = (const float*)d_in[16];
  const float* rh_w2 = (const float*)d_in[17];
  const float* rh_g2 = (const float*)d_in[18];
  const float* rh_bt2 = (const float*)d_in[19];
  const float* rh_w3 = (const float*)d_in[20];
  const float* rh_b3 = (const float*)d_in[21];
  const float* off_w = (const float*)d_in[22];
  const float* off_b = (const float*)d_in[23];
  const float* aw_w = (const float*)d_in[24];
  const float* aw_b = (const float*)d_in[25];
  const float* val_w = (const float*)d_in[26];
  const float* val_b = (const float*)d_in[27];
  const float* out_w = (const float*)d_in[28];
  const float* out_b = (const float*)d_in[29];

  float* ws = (float*)d_ws;
  float* t1 = ws + 0;                 // 4,194,304
  float* h1 = ws + 4194304;           // 4,194,304
  float* t2 = ws + 8388608;           // 2,097,152
  float* q0 = ws + 10485760;          // 4,194,304
  float* query = ws + 14680064;       // 4,194,304
  float* params = ws + 18874368;      // 524,288
  float* ymsda = ws + 19398656;       // 4,194,304
  float* Wvv = ws + 23592960;         // 16,384
  float* bvv = ws + 23609344;         // 128
  float* sums1 = ws + 23609472;       // 512
  float* sums2 = ws + 23609984;       // 512
  float* klpart = ws + 23610496;      // 128
  float* stats1 = ws + 23610624;      // 32
  float* stats2 = ws + 23610656;      // 32
  float* v = ws + 0;                  // 12,390,400 — reuses t1/h1/t2/q0 (dead by K9)

  RVConsts C = make_consts();
  dim3 blk(256);

  k_rh1_q0<<<dim3(1024, BSZ), blk, 0, stream>>>(x_rv, rh_w1, rh_b1, w_q, b_q, t1, q0, C);
  k_gnsum<128, 16><<<dim3(16, 8, BSZ), blk, 0, stream>>>(t1, sums1);
  k_gnfin<<<1, 64, 0, stream>>>(sums1, stats1, 1.0f / 262144.0f);
  k_gn1_gelu<<<16384, blk, 0, stream>>>(t1, stats1, rh_g1, rh_bt1, h1);
  k_conv3<<<dim3(1024, BSZ), blk, 0, stream>>>(h1, rh_w2, t2);
  k_gnsum<64, 8><<<dim3(16, 8, BSZ), blk, 0, stream>>>(t2, sums2);
  k_gnfin<<<1, 64, 0, stream>>>(sums2, stats2, 1.0f / 131072.0f);
  k_head<<<dim3(64, BSZ), blk, 0, stream>>>(t2, stats2, rh_g2, rh_bt2, rh_w3, rh_b3,
                                            l2e, params, klpart, C);
  k_query<<<dim3(1024, BSZ), blk, 0, stream>>>(q0, params, qs_w1, qs_b1, qs_w2, qs_b2, query);
  k_wvv<<<64, blk, 0, stream>>>(val_w, w_v, b_v, val_b, Wvv, bvv);
  k_value<<<dim3(757, BSZ), blk, 0, stream>>>(bev, Wvv, bvv, v);
  k_msda<<<dim3(1024, BSZ), blk, 0, stream>>>(query, params, off_w, off_b, aw_w, aw_b,
                                              v, out_w, out_b, ymsda);
  k_final<<<dim3(256, BSZ), blk, 0, stream>>>(ymsda, w_o, b_o, (float*)d_out);
  k_klfin<<<1, 64, 0, stream>>>(klpart, (float*)d_out);
}

// Round 2
// 1008.755 us; speedup vs baseline: 1.4253x; 1.4253x over previous
//
#include <hip/hip_runtime.h>
#include <math.h>

#define HRV 16
#define WRV 1024
#define NPIX 16384
#define NBEV 48400
#define BSZ 2

typedef __attribute__((ext_vector_type(8))) short short8;
typedef __attribute__((ext_vector_type(4))) float f32x4;

struct RVConsts {
  float steps[16];
  float means[16];
  float az_step_f;
  float pad_;
  double step_d;
  double az0;
  double az_half;
};

__device__ __forceinline__ float geluf(float x) {
  return 0.5f * x * (1.0f + erff(x * 0.70710678118654752440f));
}
__device__ __forceinline__ float sigmoidf_(float x) {
  return 1.0f / (1.0f + expf(-x));
}
__device__ __forceinline__ float softplusf_(float x) {
  return fmaxf(x, 0.0f) + log1pf(expf(-fabsf(x)));
}
__device__ __forceinline__ float azimf(int w, double step_d, double az0, double az_half) {
  double az = (double)w * step_d + az0;
  az += az_half;
  return (float)az;
}
__device__ __forceinline__ unsigned short f2bf(float f) {
  unsigned int u = __builtin_bit_cast(unsigned int, f);
  u = u + 0x7FFFu + ((u >> 16) & 1u);
  return (unsigned short)(u >> 16);
}
__device__ __forceinline__ float bf2f(unsigned short h) {
  unsigned int u = ((unsigned int)h) << 16;
  return __builtin_bit_cast(float, u);
}

// ---------------- K1: range-head conv1 (67->128) + Q0 conv (64->128) ----------------
__global__ __launch_bounds__(256) void k_rh1_q0(
    const float* __restrict__ x_rv,
    const float* __restrict__ rh_w1, const float* __restrict__ rh_b1,
    const float* __restrict__ w_q, const float* __restrict__ b_q,
    float* __restrict__ t1, float* __restrict__ q0, RVConsts C) {
  int b = blockIdx.y;
  int n0 = blockIdx.x * 16;
  int tid = threadIdx.x;
  __shared__ float xin[16][68];
  const float* src = x_rv + ((size_t)b * NPIX + n0) * 64;
  for (int i = tid; i < 16 * 64; i += 256) xin[i >> 6][i & 63] = src[i];
  if (tid < 16) {
    int n = n0 + tid;
    int h = n >> 10, w = n & 1023;
    float E = C.means[h];
    float A = azimf(w, C.step_d, C.az0, C.az_half);
    float ce = cosf(E);
    xin[tid][64] = ce * cosf(A);
    xin[tid][65] = ce * sinf(A);
    xin[tid][66] = sinf(E);
  }
  __syncthreads();
  int p = tid >> 4, co = tid & 15;
  float acc[8], accq[8];
#pragma unroll
  for (int j = 0; j < 8; j++) { acc[j] = rh_b1[co + 16 * j]; accq[j] = b_q[co + 16 * j]; }
  for (int c = 0; c < 67; c++) {
    float xv = xin[p][c];
#pragma unroll
    for (int j = 0; j < 8; j++) acc[j] += rh_w1[(size_t)(co + 16 * j) * 67 + c] * xv;
  }
  for (int c = 0; c < 64; c++) {
    float xv = xin[p][c];
#pragma unroll
    for (int j = 0; j < 8; j++) accq[j] += w_q[(size_t)(co + 16 * j) * 64 + c] * xv;
  }
  size_t base = ((size_t)b * NPIX + n0 + p) * 128;
#pragma unroll
  for (int j = 0; j < 8; j++) {
    t1[base + co + 16 * j] = acc[j];
    q0[base + co + 16 * j] = accq[j];
  }
}

// ---------------- GroupNorm partial sums (deterministic 2-stage) ----------------
template <int CCH, int CGRP>
__global__ __launch_bounds__(256) void k_gnsum(const float* __restrict__ src,
                                               float* __restrict__ sums) {
  int chunk = blockIdx.x;
  int g = blockIdx.y;
  int b = blockIdx.z;
  const int npx = NPIX / 16;
  int n0 = chunk * npx;
  int tid = threadIdx.x;
  float s = 0.f, ss = 0.f;
  const float* base = src + (size_t)b * NPIX * CCH + (size_t)g * CGRP;
  const int total = npx * CGRP;
  for (int i = tid; i < total; i += 256) {
    int n = i / CGRP;
    int cc = i % CGRP;
    float x = base[(size_t)(n0 + n) * CCH + cc];
    s += x; ss += x * x;
  }
#pragma unroll
  for (int o2 = 32; o2 > 0; o2 >>= 1) { s += __shfl_down(s, o2); ss += __shfl_down(ss, o2); }
  __shared__ float wsum[4][2];
  if ((tid & 63) == 0) { wsum[tid >> 6][0] = s; wsum[tid >> 6][1] = ss; }
  __syncthreads();
  if (tid == 0) {
    float S = wsum[0][0] + wsum[1][0] + wsum[2][0] + wsum[3][0];
    float SS = wsum[0][1] + wsum[1][1] + wsum[2][1] + wsum[3][1];
    sums[((b * 8 + g) * 16 + chunk) * 2 + 0] = S;
    sums[((b * 8 + g) * 16 + chunk) * 2 + 1] = SS;
  }
}

__global__ void k_gnfin(const float* __restrict__ sums, float* __restrict__ stats, float invN) {
  int i = threadIdx.x;
  if (i >= 16) return;
  float S = 0.f, SS = 0.f;
  for (int ch = 0; ch < 16; ch++) { S += sums[(i * 16 + ch) * 2]; SS += sums[(i * 16 + ch) * 2 + 1]; }
  float m = S * invN;
  float var = SS * invN - m * m;
  stats[i * 2] = m;
  stats[i * 2 + 1] = rsqrtf(var + 1e-5f);
}

// ---------------- K3: apply GN1 + GELU ----------------
__global__ __launch_bounds__(256) void k_gn1_gelu(
    const float* __restrict__ t1, const float* __restrict__ stats1,
    const float* __restrict__ g1, const float* __restrict__ bt1, float* __restrict__ h1) {
  size_t i = (size_t)blockIdx.x * 256 + threadIdx.x;
  int c = (int)(i & 127);
  int bidx = (int)(i >> 21);
  int g = c >> 4;
  float m = stats1[(bidx * 8 + g) * 2], is = stats1[(bidx * 8 + g) * 2 + 1];
  float x = (t1[i] - m) * is * g1[c] + bt1[c];
  h1[i] = geluf(x);
}

// ---------------- K4: 3x3 conv with circular pad (128 -> 64) ----------------
__global__ __launch_bounds__(256) void k_conv3(const float* __restrict__ h1,
                                               const float* __restrict__ w2,
                                               float* __restrict__ t2) {
  int b = blockIdx.y;
  int n0 = blockIdx.x * 16;
  int h = n0 >> 10;
  int w0 = n0 & 1023;
  int tid = threadIdx.x;
  __shared__ float tile[3][128][20];
  for (int i = tid; i < 3 * 18 * 128; i += 256) {
    int r = i / 2304;
    int rem = i - r * 2304;
    int ww = rem >> 7;
    int c = rem & 127;
    int hh = (h + r - 1 + HRV) & (HRV - 1);
    int wc = (w0 + ww - 1 + WRV) & (WRV - 1);
    tile[r][c][ww] = h1[((size_t)b * NPIX + hh * WRV + wc) * 128 + c];
  }
  __syncthreads();
  int o = tid & 63, cq = tid >> 6;
  float acc[16];
#pragma unroll
  for (int px = 0; px < 16; px++) acc[px] = 0.0f;
  for (int cc = 0; cc < 32; cc++) {
    int c = cq * 32 + cc;
#pragma unroll
    for (int ky = 0; ky < 3; ky++) {
      const float4* row4 = (const float4*)&tile[ky][c][0];
      float4 a0 = row4[0], a1 = row4[1], a2 = row4[2], a3 = row4[3], a4 = row4[4];
      float win[20] = {a0.x, a0.y, a0.z, a0.w, a1.x, a1.y, a1.z, a1.w,
                       a2.x, a2.y, a2.z, a2.w, a3.x, a3.y, a3.z, a3.w,
                       a4.x, a4.y, a4.z, a4.w};
      const float* wp = w2 + ((size_t)(o * 128 + c) * 3 + ky) * 3;
      float wv0 = wp[0], wv1 = wp[1], wv2 = wp[2];
#pragma unroll
      for (int px = 0; px < 16; px++)
        acc[px] += wv0 * win[px] + wv1 * win[px + 1] + wv2 * win[px + 2];
    }
  }
  __syncthreads();
  float* psum = &tile[0][0][0];
#pragma unroll
  for (int px = 0; px < 16; px++) psum[(cq * 16 + px) * 64 + o] = acc[px];
  __syncthreads();
  for (int j = 0; j < 4; j++) {
    int px = j * 4 + cq;
    float s = psum[(0 * 16 + px) * 64 + o] + psum[(1 * 16 + px) * 64 + o] +
              psum[(2 * 16 + px) * 64 + o] + psum[(3 * 16 + px) * 64 + o];
    t2[((size_t)b * NPIX + n0 + px) * 64 + o] = s;
  }
}

// ---------------- K6: GN2+GELU -> head(4) -> params + KL ----------------
__global__ __launch_bounds__(256) void k_head(
    const float* __restrict__ t2, const float* __restrict__ stats2,
    const float* __restrict__ g2, const float* __restrict__ bt2,
    const float* __restrict__ rh_w3, const float* __restrict__ rh_b3,
    const float* __restrict__ l2e, float* __restrict__ params,
    float* __restrict__ klpart, RVConsts C) {
  int b = blockIdx.y;
  int n = blockIdx.x * 256 + threadIdx.x;
  int h = n >> 10, w = n & 1023;
  const float* t = t2 + ((size_t)b * NPIX + n) * 64;
  float hd0 = rh_b3[0], hd1 = rh_b3[1], hd2 = rh_b3[2], hd3 = rh_b3[3];
  for (int c = 0; c < 64; c++) {
    int g = c >> 3;
    float m = stats2[(b * 8 + g) * 2], is = stats2[(b * 8 + g) * 2 + 1];
    float xv = geluf((t[c] - m) * is * g2[c] + bt2[c]);
    hd0 += rh_w3[c] * xv;
    hd1 += rh_w3[64 + c] * xv;
    hd2 += rh_w3[128 + c] * xv;
    hd3 += rh_w3[192 + c] * xv;
  }
  float mu = sigmoidf_(hd0) * 55.0f;
  float sd = softplusf_(hd1) + 1e-3f;
  float stepw = C.steps[w & 15];
  float se = sigmoidf_(hd2) * stepw + 1e-3f;
  float sa = sigmoidf_(hd3) * C.az_step_f + 1e-3f;
  float E0 = C.means[h];
  float A0 = azimf(w, C.step_d, C.az0, C.az_half);
  float* P = params + ((size_t)b * NPIX + n) * 16;
  P[0] = sd; P[1] = se; P[2] = sa;
  float M00 = l2e[0], M01 = l2e[1], M10 = l2e[4], M11 = l2e[5];
  float M20 = l2e[8], M21 = l2e[9], M30 = l2e[12], M31 = l2e[13];
#pragma unroll
  for (int k = 0; k < 5; k++) {
    float off = -0.6f + 0.3f * (float)k;
    float d = mu + sd * off;
    float E = E0 + se * off;
    float A = A0 + sa * off;
    float ce = cosf(E);
    float xl = d * ce * cosf(A), yl = d * ce * sinf(A), zl = d * sinf(E);
    float px = xl * M00 + yl * M10 + zl * M20 + M30;
    float py = xl * M01 + yl * M11 + zl * M21 + M31;
    P[3 + 2 * k] = sigmoidf_(4.0f * ((px + 55.0f) * (1.0f / 110.0f) - 0.5f));
    P[4 + 2 * k] = sigmoidf_(4.0f * ((py + 55.0f) * (1.0f / 110.0f) - 0.5f));
  }
  float mu_n = mu * (1.0f / 55.0f);
  float sr = fmaxf(sd, 1e-6f);
  float saz = sa / C.az_step_f;
  float sel = se / stepw;
  float L = 0.5f * (mu_n * mu_n + sr * sr - logf(sr * sr) - 1.0f) +
            0.5f * (saz * saz - logf(saz * saz) - 1.0f) +
            0.5f * (sel * sel - logf(sel * sel) - 1.0f);
#pragma unroll
  for (int o2 = 32; o2 > 0; o2 >>= 1) L += __shfl_down(L, o2);
  __shared__ float wsum[4];
  if ((threadIdx.x & 63) == 0) wsum[threadIdx.x >> 6] = L;
  __syncthreads();
  if (threadIdx.x == 0)
    klpart[blockIdx.y * 64 + blockIdx.x] = wsum[0] + wsum[1] + wsum[2] + wsum[3];
}

// ---------------- K7: query MLP ----------------
__global__ __launch_bounds__(256) void k_query(
    const float* __restrict__ q0, const float* __restrict__ params,
    const float* __restrict__ qs_w1, const float* __restrict__ qs_b1,
    const float* __restrict__ qs_w2, const float* __restrict__ qs_b2,
    float* __restrict__ query) {
  int b = blockIdx.y;
  int n0 = blockIdx.x * 16;
  int tid = threadIdx.x;
  __shared__ float qin[16][136];
  __shared__ float hq[16][129];
  for (int i = tid; i < 16 * 128; i += 256) {
    int p = i >> 7, c = i & 127;
    qin[p][c] = q0[((size_t)b * NPIX + n0 + p) * 128 + c];
  }
  if (tid < 16) {
    const float* P = params + ((size_t)b * NPIX + n0 + tid) * 16;
    float sd = P[0], se = P[1], sa = P[2];
    qin[tid][128] = sd; qin[tid][129] = se; qin[tid][130] = sa;
    qin[tid][131] = 1.0f / (sd + 1e-6f);
    qin[tid][132] = 1.0f / (se + 1e-6f);
    qin[tid][133] = 1.0f / (sa + 1e-6f);
  }
  __syncthreads();
  int p = tid >> 4, co = tid & 15;
  float acc[8];
#pragma unroll
  for (int j = 0; j < 8; j++) acc[j] = qs_b1[co + 16 * j];
  for (int c = 0; c < 134; c++) {
    float xv = qin[p][c];
#pragma unroll
    for (int j = 0; j < 8; j++) acc[j] += qs_w1[(size_t)(co + 16 * j) * 134 + c] * xv;
  }
#pragma unroll
  for (int j = 0; j < 8; j++) hq[p][co + 16 * j] = geluf(acc[j]);
  __syncthreads();
#pragma unroll
  for (int j = 0; j < 8; j++) acc[j] = qs_b2[co + 16 * j];
  for (int c = 0; c < 128; c++) {
    float xv = hq[p][c];
#pragma unroll
    for (int j = 0; j < 8; j++) acc[j] += qs_w2[(size_t)(co + 16 * j) * 128 + c] * xv;
  }
  size_t base = ((size_t)b * NPIX + n0 + p) * 128;
#pragma unroll
  for (int j = 0; j < 8; j++) query[base + co + 16 * j] = acc[j];
}

// ---------------- K8: pack weights to bf16 (Wvv fold, projW pad-512, outW) ----------------
__global__ __launch_bounds__(256) void k_pack(
    const float* __restrict__ val_w, const float* __restrict__ w_v,
    const float* __restrict__ b_v, const float* __restrict__ val_b,
    const float* __restrict__ off_w, const float* __restrict__ off_b,
    const float* __restrict__ aw_w, const float* __restrict__ aw_b,
    const float* __restrict__ out_w,
    unsigned short* __restrict__ wvv_bf, float* __restrict__ bvv,
    unsigned short* __restrict__ projW, float* __restrict__ projB,
    unsigned short* __restrict__ outW) {
  int idx = blockIdx.x * 256 + threadIdx.x;
  if (idx < 16384) {
    int o = idx >> 7, c = idx & 127;
    float acc = 0.0f;
    for (int m = 0; m < 128; m++) acc += val_w[o * 128 + m] * w_v[m * 128 + c];
    wvv_bf[idx] = f2bf(acc);
  } else if (idx < 16512) {
    int o = idx - 16384;
    float acc = val_b[o];
    for (int m = 0; m < 128; m++) acc += val_w[o * 128 + m] * b_v[m];
    bvv[o] = acc;
  } else if (idx < 82048) {
    int j = idx - 16512;
    int r = j >> 7, c = j & 127;
    float w = (r < 320) ? off_w[r * 128 + c] : ((r < 480) ? aw_w[(r - 320) * 128 + c] : 0.0f);
    projW[j] = f2bf(w);
  } else if (idx < 82560) {
    int r = idx - 82048;
    projB[r] = (r < 320) ? off_b[r] : ((r < 480) ? aw_b[r - 320] : 0.0f);
  } else if (idx < 98944) {
    int j = idx - 82560;
    outW[j] = f2bf(out_w[j]);
  }
}

// ---------------- K9: MFMA value projection v[b,p,o] = Wvv@bev + bvv (bf16 out) ----------------
__global__ __launch_bounds__(256) void k_value(
    const float* __restrict__ bev, const unsigned short* __restrict__ wvv_bf,
    const float* __restrict__ bvv, unsigned short* __restrict__ v) {
  __shared__ float lds[128 * 66];
  int b = blockIdx.y;
  int p0 = blockIdx.x * 64;
  int tid = threadIdx.x;
  int npx = NBEV - p0; if (npx > 64) npx = 64;
  for (int i = tid; i < 128 * 64; i += 256) {
    int c = i >> 6, p = i & 63;
    lds[c * 66 + p] = (p < npx) ? bev[((size_t)b * 128 + c) * NBEV + p0 + p] : 0.0f;
  }
  __syncthreads();
  int wave = tid >> 6, l = tid & 63;
  int lr = l & 15, lk = l >> 4;
  int ploc = wave * 16 + lr;
  f32x4 acc[8];
#pragma unroll
  for (int nt = 0; nt < 8; nt++) {
    float bias = bvv[nt * 16 + lr];
    acc[nt] = (f32x4){bias, bias, bias, bias};
  }
#pragma unroll
  for (int ks = 0; ks < 4; ks++) {
    int k0 = ks * 32 + lk * 8;
    short8 a;
#pragma unroll
    for (int j = 0; j < 8; j++) a[j] = (short)f2bf(lds[(k0 + j) * 66 + ploc]);
#pragma unroll
    for (int nt = 0; nt < 8; nt++) {
      short8 bf = *(const short8*)(wvv_bf + (size_t)(nt * 16 + lr) * 128 + k0);
      acc[nt] = __builtin_amdgcn_mfma_f32_16x16x32_bf16(a, bf, acc[nt], 0, 0, 0);
    }
  }
#pragma unroll
  for (int nt = 0; nt < 8; nt++) {
    int n = nt * 16 + lr;
#pragma unroll
    for (int r = 0; r < 4; r++) {
      int p = p0 + wave * 16 + lk * 4 + r;
      if (p < NBEV) v[((size_t)b * NBEV + p) * 128 + n] = f2bf(acc[nt][r]);
    }
  }
}

// ---------------- K10: MFMA projection (query -> 512 outs, bf16) ----------------
__global__ __launch_bounds__(256) void k_proj(
    const float* __restrict__ query, const unsigned short* __restrict__ projW,
    const float* __restrict__ projB, unsigned short* __restrict__ proj) {
  int b = blockIdx.z;
  int wave = threadIdx.x >> 6, l = threadIdx.x & 63;
  int lr = l & 15, lk = l >> 4;
  int p0 = blockIdx.x * 64 + wave * 16;
  int n0 = blockIdx.y * 128;
  f32x4 acc[8];
#pragma unroll
  for (int nt = 0; nt < 8; nt++) {
    float bias = projB[n0 + nt * 16 + lr];
    acc[nt] = (f32x4){bias, bias, bias, bias};
  }
  const float* ap = query + ((size_t)b * NPIX + p0 + lr) * 128 + lk * 8;
#pragma unroll
  for (int ks = 0; ks < 4; ks++) {
    float4 a0 = *(const float4*)(ap + ks * 32);
    float4 a1 = *(const float4*)(ap + ks * 32 + 4);
    short8 a;
    a[0] = (short)f2bf(a0.x); a[1] = (short)f2bf(a0.y);
    a[2] = (short)f2bf(a0.z); a[3] = (short)f2bf(a0.w);
    a[4] = (short)f2bf(a1.x); a[5] = (short)f2bf(a1.y);
    a[6] = (short)f2bf(a1.z); a[7] = (short)f2bf(a1.w);
#pragma unroll
    for (int nt = 0; nt < 8; nt++) {
      short8 bf = *(const short8*)(projW + (size_t)(n0 + nt * 16 + lr) * 128 + ks * 32 + lk * 8);
      acc[nt] = __builtin_amdgcn_mfma_f32_16x16x32_bf16(a, bf, acc[nt], 0, 0, 0);
    }
  }
#pragma unroll
  for (int nt = 0; nt < 8; nt++) {
    int n = n0 + nt * 16 + lr;
#pragma unroll
    for (int r = 0; r < 4; r++) {
      int p = p0 + lk * 4 + r;
      proj[((size_t)b * NPIX + p) * 512 + n] = f2bf(acc[nt][r]);
    }
  }
}

// ---------------- K11: sampler (4 threads per (pixel,head)) ----------------
__global__ __launch_bounds__(256) void k_samp(
    const unsigned short* __restrict__ proj, const float* __restrict__ params,
    const unsigned short* __restrict__ v, unsigned short* __restrict__ S) {
  int b = blockIdx.y;
  int bid = blockIdx.x;
  int pb = (bid & 7) * 256 + (bid >> 3);  // XCD-chunked swizzle (2048 = 8*256)
  int tid = threadIdx.x;
  int q = tid & 3, hh = (tid >> 2) & 7, pl = tid >> 5;
  int n = pb * 8 + pl;
  const unsigned short* base = proj + ((size_t)b * NPIX + n) * 512;
  float mx = -1e30f;
#pragma unroll
  for (int i = 0; i < 20; i++) mx = fmaxf(mx, bf2f(base[320 + hh * 20 + i]));
  float s = 0.0f;
#pragma unroll
  for (int i = 0; i < 20; i++) s += expf(bf2f(base[320 + hh * 20 + i]) - mx);
  float rs = 1.0f / s;
  const float* P = params + ((size_t)b * NPIX + n) * 16;
  const unsigned short* vb = v + (size_t)b * NBEV * 128 + hh * 16 + q * 4;
  float ac0 = 0.f, ac1 = 0.f, ac2 = 0.f, ac3 = 0.f;
  for (int kp = 0; kp < 20; kp++) {
    int k = kp >> 2, pp = kp & 3;
    float lx = P[3 + 2 * k] + bf2f(base[hh * 40 + k * 8 + pp * 2 + 0]) * (1.0f / 220.0f);
    float ly = P[4 + 2 * k] + bf2f(base[hh * 40 + k * 8 + pp * 2 + 1]) * (1.0f / 220.0f);
    float a = expf(bf2f(base[320 + hh * 20 + kp]) - mx) * rs;
    float X = lx * 220.0f - 0.5f;
    float Y = ly * 220.0f - 0.5f;
    float xf = floorf(X), yf = floorf(Y);
    float wx = X - xf, wy = Y - yf;
    int x0 = (int)xf, y0 = (int)yf;
#pragma unroll
    for (int dy = 0; dy < 2; dy++) {
      int yi = y0 + dy;
      if (yi < 0 || yi >= 220) continue;
      float wyv = dy ? wy : (1.0f - wy);
#pragma unroll
      for (int dx = 0; dx < 2; dx++) {
        int xi = x0 + dx;
        if (xi < 0 || xi >= 220) continue;
        float wgt = a * wyv * (dx ? wx : (1.0f - wx));
        uint2 raw = *(const uint2*)(vb + (size_t)(yi * 220 + xi) * 128);
        ac0 += wgt * bf2f((unsigned short)(raw.x & 0xffffu));
        ac1 += wgt * bf2f((unsigned short)(raw.x >> 16));
        ac2 += wgt * bf2f((unsigned short)(raw.y & 0xffffu));
        ac3 += wgt * bf2f((unsigned short)(raw.y >> 16));
      }
    }
  }
  uint2 outp;
  outp.x = (unsigned int)f2bf(ac0) | ((unsigned int)f2bf(ac1) << 16);
  outp.y = (unsigned int)f2bf(ac2) | ((unsigned int)f2bf(ac3) << 16);
  *(uint2*)(S + ((size_t)b * NPIX + n) * 128 + hh * 16 + q * 4) = outp;
}

// ---------------- K12: MFMA out-projection + residual -> ymsda f32 ----------------
__global__ __launch_bounds__(256) void k_out(
    const unsigned short* __restrict__ S, const unsigned short* __restrict__ outW,
    const float* __restrict__ out_b, const float* __restrict__ query,
    float* __restrict__ ymsda) {
  int b = blockIdx.y;
  int wave = threadIdx.x >> 6, l = threadIdx.x & 63;
  int lr = l & 15, lk = l >> 4;
  int p0 = blockIdx.x * 64 + wave * 16;
  f32x4 acc[8];
#pragma unroll
  for (int nt = 0; nt < 8; nt++) {
    float bias = out_b[nt * 16 + lr];
    acc[nt] = (f32x4){bias, bias, bias, bias};
  }
  const unsigned short* ap = S + ((size_t)b * NPIX + p0 + lr) * 128 + lk * 8;
#pragma unroll
  for (int ks = 0; ks < 4; ks++) {
    short8 a = *(const short8*)(ap + ks * 32);
#pragma unroll
    for (int nt = 0; nt < 8; nt++) {
      short8 bf = *(const short8*)(outW + (size_t)(nt * 16 + lr) * 128 + ks * 32 + lk * 8);
      acc[nt] = __builtin_amdgcn_mfma_f32_16x16x32_bf16(a, bf, acc[nt], 0, 0, 0);
    }
  }
#pragma unroll
  for (int nt = 0; nt < 8; nt++) {
    int n = nt * 16 + lr;
#pragma unroll
    for (int r = 0; r < 4; r++) {
      int p = p0 + lk * 4 + r;
      size_t o = ((size_t)b * NPIX + p) * 128 + n;
      ymsda[o] = acc[nt][r] + query[o];
    }
  }
}

// ---------------- K13: final conv1x1 (w_o) with NCHW-ordered output ----------------
__global__ __launch_bounds__(256) void k_final(
    const float* __restrict__ ymsda, const float* __restrict__ w_o,
    const float* __restrict__ b_o, float* __restrict__ out) {
  int b = blockIdx.y;
  int n0 = blockIdx.x * 64;
  int tid = threadIdx.x;
  __shared__ float yt[128][68];
  for (int i = tid; i < 64 * 128; i += 256) {
    int p = i >> 7, c = i & 127;
    yt[c][p] = ymsda[((size_t)b * NPIX + n0 + p) * 128 + c];
  }
  __syncthreads();
  int ob = (tid & 31) * 4;
  int pxg = tid >> 5;
  float acc[4][8];
#pragma unroll
  for (int j = 0; j < 4; j++) {
    float bz = b_o[ob + j];
#pragma unroll
    for (int i = 0; i < 8; i++) acc[j][i] = bz;
  }
  for (int c = 0; c < 128; c++) {
    const float4* row = (const float4*)&yt[c][pxg * 8];
    float4 r0 = row[0], r1 = row[1];
    float pxv[8] = {r0.x, r0.y, r0.z, r0.w, r1.x, r1.y, r1.z, r1.w};
#pragma unroll
    for (int j = 0; j < 4; j++) {
      float wv = w_o[(size_t)(ob + j) * 128 + c];
#pragma unroll
      for (int i = 0; i < 8; i++) acc[j][i] += wv * pxv[i];
    }
  }
#pragma unroll
  for (int j = 0; j < 4; j++) {
    float* dst = out + (size_t)(b * 128 + ob + j) * NPIX + n0 + pxg * 8;
    float4 s0 = {acc[j][0], acc[j][1], acc[j][2], acc[j][3]};
    float4 s1 = {acc[j][4], acc[j][5], acc[j][6], acc[j][7]};
    *(float4*)dst = s0;
    *(float4*)(dst + 4) = s1;
  }
}

__global__ void k_klfin(const float* __restrict__ klpart, float* __restrict__ out) {
  if (threadIdx.x == 0) {
    float s = 0.0f;
    for (int i = 0; i < 128; i++) s += klpart[i];
    out[(size_t)BSZ * 128 * NPIX] = 1e-4f * (s / 32768.0f);
  }
}

// ---------------- host ----------------
static RVConsts make_consts() {
  static const float ELEV[32] = {
      -30.67f, -29.33f, -28.0f, -26.66f, -25.33f, -24.0f, -22.67f, -21.33f,
      -20.0f,  -18.67f, -17.33f, -16.0f, -14.67f, -13.33f, -12.0f, -10.67f,
      -9.33f,  -8.0f,   -6.66f,  -5.33f, -4.0f,   -2.67f,  -1.33f, 0.0f,
      1.33f,   2.67f,   4.0f,    5.33f,  6.67f,   8.0f,    9.33f,  10.67f};
  RVConsts C;
  const float d2r = 0.017453292519943295f;
  for (int r = 0; r < 16; r++) {
    float a = ELEV[31 - 2 * r], b = ELEV[30 - 2 * r];
    float mx = fmaxf(a, b), mn = fminf(a, b);
    C.steps[r] = (mx - mn) * d2r;
    C.means[r] = ((a + b) * 0.5f) * d2r;
  }
  const double PI_D = 3.14159265358979323846;
  double step_d = (PI_D - (-PI_D)) / 1024.0;
  double az0 = -PI_D;
  double az1 = az0 + step_d;
  double az_step_d = az1 - az0;
  C.az_step_f = (float)az_step_d;
  C.pad_ = 0.0f;
  C.step_d = step_d;
  C.az0 = az0;
  C.az_half = az_step_d * 0.5;
  return C;
}

// Workspace layout (f32 words). Peak 21,497,024 words = 86.0 MB (< proven 94.4 MB).
#define OFF_T1     0u          /* 4,194,304 ; later overlaid by proj_bf then ymsda */
#define OFF_H1     4194304u    /* 4,194,304 ; later overlaid by proj_bf */
#define OFF_T2     8388608u    /* 2,097,152 ; later overlaid by v_bf */
#define OFF_Q0     10485760u   /* 4,194,304 ; later overlaid by v_bf + lateW */
#define OFF_PARAMS 14680064u   /* 524,288 */
#define OFF_QUERY  15204352u   /* 4,194,304 */
#define OFF_S      19398656u   /* 2,097,152 (bf16 x 4,194,304) */
#define OFF_SUMS1  21495808u
#define OFF_SUMS2  21496320u
#define OFF_STATS1 21496832u
#define OFF_STATS2 21496864u
#define OFF_KL     21496896u
#define OFF_PROJ   0u          /* bf16 x 16,777,216 = 8,388,608 w (after conv3) */
#define OFF_V      8388608u    /* bf16 x 12,390,400 = 6,195,200 w (after head+query) */
#define OFF_WVV    14583808u   /* bf16 x 16384 */
#define OFF_BVV    14592000u   /* f32 x 128 */
#define OFF_PROJW  14592128u   /* bf16 x 65536 */
#define OFF_PROJB  14624896u   /* f32 x 512 */
#define OFF_OUTW   14625408u   /* bf16 x 16384 */
#define OFF_YMSDA  0u          /* f32 x 4,194,304 (after samp consumes proj) */

extern "C" void kernel_launch(void* const* d_in, const int* in_sizes, int n_in,
                              void* d_out, int out_size, void* d_ws, size_t ws_size,
                              hipStream_t stream) {
  const float* x_rv = (const float*)d_in[0];
  const float* bev = (const float*)d_in[1];
  const float* l2e = (const float*)d_in[2];
  const float* w_q = (const float*)d_in[3];
  const float* b_q = (const float*)d_in[4];
  const float* w_v = (const float*)d_in[5];
  const float* b_v = (const float*)d_in[6];
  const float* w_o = (const float*)d_in[7];
  const float* b_o = (const float*)d_in[8];
  const float* qs_w1 = (const float*)d_in[9];
  const float* qs_b1 = (const float*)d_in[10];
  const float* qs_w2 = (const float*)d_in[11];
  const float* qs_b2 = (const float*)d_in[12];
  const float* rh_w1 = (const float*)d_in[13];
  const float* rh_b1 = (const float*)d_in[14];
  const float* rh_g1 = (const float*)d_in[15];
  const float* rh_bt1 = (const float*)d_in[16];
  const float* rh_w2 = (const float*)d_in[17];
  const float* rh_g2 = (const float*)d_in[18];
  const float* rh_bt2 = (const float*)d_in[19];
  const float* rh_w3 = (const float*)d_in[20];
  const float* rh_b3 = (const float*)d_in[21];
  const float* off_w = (const float*)d_in[22];
  const float* off_b = (const float*)d_in[23];
  const float* aw_w = (const float*)d_in[24];
  const float* aw_b = (const float*)d_in[25];
  const float* val_w = (const float*)d_in[26];
  const float* val_b = (const float*)d_in[27];
  const float* out_w = (const float*)d_in[28];
  const float* out_b = (const float*)d_in[29];

  float* ws = (float*)d_ws;
  float* t1 = ws + OFF_T1;
  float* h1 = ws + OFF_H1;
  float* t2 = ws + OFF_T2;
  float* q0 = ws + OFF_Q0;
  float* params = ws + OFF_PARAMS;
  float* query = ws + OFF_QUERY;
  float* sums1 = ws + OFF_SUMS1;
  float* sums2 = ws + OFF_SUMS2;
  float* stats1 = ws + OFF_STATS1;
  float* stats2 = ws + OFF_STATS2;
  float* klpart = ws + OFF_KL;
  float* bvv = ws + OFF_BVV;
  float* projB = ws + OFF_PROJB;
  float* ymsda = ws + OFF_YMSDA;
  unsigned short* S_bf = (unsigned short*)(ws + OFF_S);
  unsigned short* proj_bf = (unsigned short*)(ws + OFF_PROJ);
  unsigned short* v_bf = (unsigned short*)(ws + OFF_V);
  unsigned short* wvv_bf = (unsigned short*)(ws + OFF_WVV);
  unsigned short* projW = (unsigned short*)(ws + OFF_PROJW);
  unsigned short* outW = (unsigned short*)(ws + OFF_OUTW);

  RVConsts C = make_consts();
  dim3 blk(256);

  k_rh1_q0<<<dim3(1024, BSZ), blk, 0, stream>>>(x_rv, rh_w1, rh_b1, w_q, b_q, t1, q0, C);
  k_gnsum<128, 16><<<dim3(16, 8, BSZ), blk, 0, stream>>>(t1, sums1);
  k_gnfin<<<1, 64, 0, stream>>>(sums1, stats1, 1.0f / 262144.0f);
  k_gn1_gelu<<<16384, blk, 0, stream>>>(t1, stats1, rh_g1, rh_bt1, h1);
  k_conv3<<<dim3(1024, BSZ), blk, 0, stream>>>(h1, rh_w2, t2);
  k_gnsum<64, 8><<<dim3(16, 8, BSZ), blk, 0, stream>>>(t2, sums2);
  k_gnfin<<<1, 64, 0, stream>>>(sums2, stats2, 1.0f / 131072.0f);
  k_head<<<dim3(64, BSZ), blk, 0, stream>>>(t2, stats2, rh_g2, rh_bt2, rh_w3, rh_b3,
                                            l2e, params, klpart, C);
  k_query<<<dim3(1024, BSZ), blk, 0, stream>>>(q0, params, qs_w1, qs_b1, qs_w2, qs_b2, query);
  k_pack<<<387, blk, 0, stream>>>(val_w, w_v, b_v, val_b, off_w, off_b, aw_w, aw_b, out_w,
                                  wvv_bf, bvv, projW, projB, outW);
  k_value<<<dim3(757, BSZ), blk, 0, stream>>>(bev, wvv_bf, bvv, v_bf);
  k_proj<<<dim3(256, 4, BSZ), blk, 0, stream>>>(query, projW, projB, proj_bf);
  k_samp<<<dim3(2048, BSZ), blk, 0, stream>>>(proj_bf, params, v_bf, S_bf);
  k_out<<<dim3(256, BSZ), blk, 0, stream>>>(S_bf, outW, out_b, query, ymsda);
  k_final<<<dim3(256, BSZ), blk, 0, stream>>>(ymsda, w_o, b_o, (float*)d_out);
  k_klfin<<<1, 64, 0, stream>>>(klpart, (float*)d_out);
}

// Round 3
// 439.294 us; speedup vs baseline: 3.2729x; 2.2963x over previous
//
#include <hip/hip_runtime.h>
#include <math.h>

#define HRV 16
#define WRV 1024
#define NPIX 16384
#define NBEV 48400
#define BSZ 2

typedef __attribute__((ext_vector_type(8))) short short8;
typedef __attribute__((ext_vector_type(4))) float f32x4;

struct RVConsts {
  float steps[16];
  float means[16];
  float az_step_f;
  float pad_;
  double step_d;
  double az0;
  double az_half;
};

__device__ __forceinline__ float geluf(float x) {
  return 0.5f * x * (1.0f + erff(x * 0.70710678118654752440f));
}
__device__ __forceinline__ float sigmoidf_(float x) {
  return 1.0f / (1.0f + expf(-x));
}
__device__ __forceinline__ float softplusf_(float x) {
  return fmaxf(x, 0.0f) + log1pf(expf(-fabsf(x)));
}
__device__ __forceinline__ float azimf(int w, double step_d, double az0, double az_half) {
  double az = (double)w * step_d + az0;
  az += az_half;
  return (float)az;
}
__device__ __forceinline__ unsigned short f2bf(float f) {
  unsigned int u = __builtin_bit_cast(unsigned int, f);
  u = u + 0x7FFFu + ((u >> 16) & 1u);
  return (unsigned short)(u >> 16);
}
__device__ __forceinline__ float bf2f(unsigned short h) {
  unsigned int u = ((unsigned int)h) << 16;
  return __builtin_bit_cast(float, u);
}

// ---------------- K1: MFMA range-head conv1 (67->128) + Q0 conv (64->128) ----------------
// Shared A fragment (x_rv + u_vec padded to K=96); both weight mats K-padded with zeros.
__global__ __launch_bounds__(256) void k_rh1_q0(
    const float* __restrict__ x_rv,
    const unsigned short* __restrict__ rhW1p, const float* __restrict__ rh_b1,
    const unsigned short* __restrict__ wqp, const float* __restrict__ b_q,
    float* __restrict__ t1, float* __restrict__ q0, RVConsts C) {
  __shared__ unsigned short xin[64][104];  // 13.3 KB, stride 208B (2-way banks)
  int b = blockIdx.y;
  int n0 = blockIdx.x * 64;
  int tid = threadIdx.x;
  const float* src = x_rv + ((size_t)b * NPIX + n0) * 64;
  for (int i = tid; i < 1024; i += 256) {
    int p = i >> 4, c = (i & 15) * 4;
    float4 v4 = *(const float4*)(src + p * 64 + c);
    xin[p][c] = f2bf(v4.x);
    xin[p][c + 1] = f2bf(v4.y);
    xin[p][c + 2] = f2bf(v4.z);
    xin[p][c + 3] = f2bf(v4.w);
  }
  if (tid < 64) {
    int n = n0 + tid;
    int h = n >> 10, w = n & 1023;
    float E = C.means[h];
    float A = azimf(w, C.step_d, C.az0, C.az_half);
    float ce = cosf(E);
    xin[tid][64] = f2bf(ce * cosf(A));
    xin[tid][65] = f2bf(ce * sinf(A));
    xin[tid][66] = f2bf(sinf(E));
    for (int c = 67; c < 104; c++) xin[tid][c] = 0;
  }
  __syncthreads();
  int wave = tid >> 6, l = tid & 63;
  int lr = l & 15, lk = l >> 4;
  f32x4 acc[8], accq[8];
#pragma unroll
  for (int nt = 0; nt < 8; nt++) {
    float b1 = rh_b1[nt * 16 + lr], b2 = b_q[nt * 16 + lr];
    acc[nt] = (f32x4){b1, b1, b1, b1};
    accq[nt] = (f32x4){b2, b2, b2, b2};
  }
#pragma unroll
  for (int ks = 0; ks < 3; ks++) {
    short8 a = *(const short8*)&xin[wave * 16 + lr][ks * 32 + lk * 8];
#pragma unroll
    for (int nt = 0; nt < 8; nt++) {
      short8 b1v = *(const short8*)(rhW1p + (size_t)(nt * 16 + lr) * 96 + ks * 32 + lk * 8);
      acc[nt] = __builtin_amdgcn_mfma_f32_16x16x32_bf16(a, b1v, acc[nt], 0, 0, 0);
      short8 b2v = *(const short8*)(wqp + (size_t)(nt * 16 + lr) * 96 + ks * 32 + lk * 8);
      accq[nt] = __builtin_amdgcn_mfma_f32_16x16x32_bf16(a, b2v, accq[nt], 0, 0, 0);
    }
  }
#pragma unroll
  for (int nt = 0; nt < 8; nt++) {
    int n = nt * 16 + lr;
#pragma unroll
    for (int r = 0; r < 4; r++) {
      int p = n0 + wave * 16 + lk * 4 + r;
      size_t o = ((size_t)b * NPIX + p) * 128 + n;
      t1[o] = acc[nt][r];
      q0[o] = accq[nt][r];
    }
  }
}

// ---------------- GroupNorm partial sums (deterministic 2-stage) ----------------
template <int CCH, int CGRP>
__global__ __launch_bounds__(256) void k_gnsum(const float* __restrict__ src,
                                               float* __restrict__ sums) {
  int chunk = blockIdx.x;
  int g = blockIdx.y;
  int b = blockIdx.z;
  const int npx = NPIX / 16;
  int n0 = chunk * npx;
  int tid = threadIdx.x;
  float s = 0.f, ss = 0.f;
  const float* base = src + (size_t)b * NPIX * CCH + (size_t)g * CGRP;
  const int total = npx * CGRP;
  for (int i = tid; i < total; i += 256) {
    int n = i / CGRP;
    int cc = i % CGRP;
    float x = base[(size_t)(n0 + n) * CCH + cc];
    s += x; ss += x * x;
  }
#pragma unroll
  for (int o2 = 32; o2 > 0; o2 >>= 1) { s += __shfl_down(s, o2); ss += __shfl_down(ss, o2); }
  __shared__ float wsum[4][2];
  if ((tid & 63) == 0) { wsum[tid >> 6][0] = s; wsum[tid >> 6][1] = ss; }
  __syncthreads();
  if (tid == 0) {
    float S = wsum[0][0] + wsum[1][0] + wsum[2][0] + wsum[3][0];
    float SS = wsum[0][1] + wsum[1][1] + wsum[2][1] + wsum[3][1];
    sums[((b * 8 + g) * 16 + chunk) * 2 + 0] = S;
    sums[((b * 8 + g) * 16 + chunk) * 2 + 1] = SS;
  }
}

__global__ void k_gnfin(const float* __restrict__ sums, float* __restrict__ stats, float invN) {
  int i = threadIdx.x;
  if (i >= 16) return;
  float S = 0.f, SS = 0.f;
  for (int ch = 0; ch < 16; ch++) { S += sums[(i * 16 + ch) * 2]; SS += sums[(i * 16 + ch) * 2 + 1]; }
  float m = S * invN;
  float var = SS * invN - m * m;
  stats[i * 2] = m;
  stats[i * 2 + 1] = rsqrtf(var + 1e-5f);
}

// ---------------- K3: apply GN1 + GELU ----------------
__global__ __launch_bounds__(256) void k_gn1_gelu(
    const float* __restrict__ t1, const float* __restrict__ stats1,
    const float* __restrict__ g1, const float* __restrict__ bt1, float* __restrict__ h1) {
  size_t i = (size_t)blockIdx.x * 256 + threadIdx.x;
  int c = (int)(i & 127);
  int bidx = (int)(i >> 21);
  int g = c >> 4;
  float m = stats1[(bidx * 8 + g) * 2], is = stats1[(bidx * 8 + g) * 2 + 1];
  float x = (t1[i] - m) * is * g1[c] + bt1[c];
  h1[i] = geluf(x);
}

// ---------------- K4: 3x3 conv with circular pad (128 -> 64) ----------------
__global__ __launch_bounds__(256) void k_conv3(const float* __restrict__ h1,
                                               const float* __restrict__ w2,
                                               float* __restrict__ t2) {
  int b = blockIdx.y;
  int n0 = blockIdx.x * 16;
  int h = n0 >> 10;
  int w0 = n0 & 1023;
  int tid = threadIdx.x;
  __shared__ float tile[3][128][20];
  for (int i = tid; i < 3 * 18 * 128; i += 256) {
    int r = i / 2304;
    int rem = i - r * 2304;
    int ww = rem >> 7;
    int c = rem & 127;
    int hh = (h + r - 1 + HRV) & (HRV - 1);
    int wc = (w0 + ww - 1 + WRV) & (WRV - 1);
    tile[r][c][ww] = h1[((size_t)b * NPIX + hh * WRV + wc) * 128 + c];
  }
  __syncthreads();
  int o = tid & 63, cq = tid >> 6;
  float acc[16];
#pragma unroll
  for (int px = 0; px < 16; px++) acc[px] = 0.0f;
  for (int cc = 0; cc < 32; cc++) {
    int c = cq * 32 + cc;
#pragma unroll
    for (int ky = 0; ky < 3; ky++) {
      const float4* row4 = (const float4*)&tile[ky][c][0];
      float4 a0 = row4[0], a1 = row4[1], a2 = row4[2], a3 = row4[3], a4 = row4[4];
      float win[20] = {a0.x, a0.y, a0.z, a0.w, a1.x, a1.y, a1.z, a1.w,
                       a2.x, a2.y, a2.z, a2.w, a3.x, a3.y, a3.z, a3.w,
                       a4.x, a4.y, a4.z, a4.w};
      const float* wp = w2 + ((size_t)(o * 128 + c) * 3 + ky) * 3;
      float wv0 = wp[0], wv1 = wp[1], wv2 = wp[2];
#pragma unroll
      for (int px = 0; px < 16; px++)
        acc[px] += wv0 * win[px] + wv1 * win[px + 1] + wv2 * win[px + 2];
    }
  }
  __syncthreads();
  float* psum = &tile[0][0][0];
#pragma unroll
  for (int px = 0; px < 16; px++) psum[(cq * 16 + px) * 64 + o] = acc[px];
  __syncthreads();
  for (int j = 0; j < 4; j++) {
    int px = j * 4 + cq;
    float s = psum[(0 * 16 + px) * 64 + o] + psum[(1 * 16 + px) * 64 + o] +
              psum[(2 * 16 + px) * 64 + o] + psum[(3 * 16 + px) * 64 + o];
    t2[((size_t)b * NPIX + n0 + px) * 64 + o] = s;
  }
}

// ---------------- K6: GN2+GELU -> head(4) -> params + KL ----------------
__global__ __launch_bounds__(256) void k_head(
    const float* __restrict__ t2, const float* __restrict__ stats2,
    const float* __restrict__ g2, const float* __restrict__ bt2,
    const float* __restrict__ rh_w3, const float* __restrict__ rh_b3,
    const float* __restrict__ l2e, float* __restrict__ params,
    float* __restrict__ klpart, RVConsts C) {
  int b = blockIdx.y;
  int n = blockIdx.x * 256 + threadIdx.x;
  int h = n >> 10, w = n & 1023;
  const float* t = t2 + ((size_t)b * NPIX + n) * 64;
  float hd0 = rh_b3[0], hd1 = rh_b3[1], hd2 = rh_b3[2], hd3 = rh_b3[3];
  for (int c = 0; c < 64; c++) {
    int g = c >> 3;
    float m = stats2[(b * 8 + g) * 2], is = stats2[(b * 8 + g) * 2 + 1];
    float xv = geluf((t[c] - m) * is * g2[c] + bt2[c]);
    hd0 += rh_w3[c] * xv;
    hd1 += rh_w3[64 + c] * xv;
    hd2 += rh_w3[128 + c] * xv;
    hd3 += rh_w3[192 + c] * xv;
  }
  float mu = sigmoidf_(hd0) * 55.0f;
  float sd = softplusf_(hd1) + 1e-3f;
  float stepw = C.steps[w & 15];
  float se = sigmoidf_(hd2) * stepw + 1e-3f;
  float sa = sigmoidf_(hd3) * C.az_step_f + 1e-3f;
  float E0 = C.means[h];
  float A0 = azimf(w, C.step_d, C.az0, C.az_half);
  float* P = params + ((size_t)b * NPIX + n) * 16;
  P[0] = sd; P[1] = se; P[2] = sa;
  float M00 = l2e[0], M01 = l2e[1], M10 = l2e[4], M11 = l2e[5];
  float M20 = l2e[8], M21 = l2e[9], M30 = l2e[12], M31 = l2e[13];
#pragma unroll
  for (int k = 0; k < 5; k++) {
    float off = -0.6f + 0.3f * (float)k;
    float d = mu + sd * off;
    float E = E0 + se * off;
    float A = A0 + sa * off;
    float ce = cosf(E);
    float xl = d * ce * cosf(A), yl = d * ce * sinf(A), zl = d * sinf(E);
    float px = xl * M00 + yl * M10 + zl * M20 + M30;
    float py = xl * M01 + yl * M11 + zl * M21 + M31;
    P[3 + 2 * k] = sigmoidf_(4.0f * ((px + 55.0f) * (1.0f / 110.0f) - 0.5f));
    P[4 + 2 * k] = sigmoidf_(4.0f * ((py + 55.0f) * (1.0f / 110.0f) - 0.5f));
  }
  float mu_n = mu * (1.0f / 55.0f);
  float sr = fmaxf(sd, 1e-6f);
  float saz = sa / C.az_step_f;
  float sel = se / stepw;
  float L = 0.5f * (mu_n * mu_n + sr * sr - logf(sr * sr) - 1.0f) +
            0.5f * (saz * saz - logf(saz * saz) - 1.0f) +
            0.5f * (sel * sel - logf(sel * sel) - 1.0f);
#pragma unroll
  for (int o2 = 32; o2 > 0; o2 >>= 1) L += __shfl_down(L, o2);
  __shared__ float wsum[4];
  if ((threadIdx.x & 63) == 0) wsum[threadIdx.x >> 6] = L;
  __syncthreads();
  if (threadIdx.x == 0)
    klpart[blockIdx.y * 64 + blockIdx.x] = wsum[0] + wsum[1] + wsum[2] + wsum[3];
}

// ---------------- K7: MFMA query MLP (K=128 MFMA + f32 sig-feature tail) ----------------
__global__ __launch_bounds__(256) void k_query(
    const float* __restrict__ q0, const float* __restrict__ params,
    const unsigned short* __restrict__ qsW1p, const float* __restrict__ qs_b1,
    const float* __restrict__ qs_w1f,
    const unsigned short* __restrict__ qsW2p, const float* __restrict__ qs_b2,
    float* __restrict__ query) {
  __shared__ unsigned short qin[64][136];  // bf16 q0, stride 272B
  __shared__ unsigned short hq[64][136];   // bf16 hidden
  __shared__ float sigf[64][6];
  int b = blockIdx.y;
  int n0 = blockIdx.x * 64;
  int tid = threadIdx.x;
  const float* src = q0 + ((size_t)b * NPIX + n0) * 128;
  for (int i = tid; i < 2048; i += 256) {
    int p = i >> 5, c = (i & 31) * 4;
    float4 v4 = *(const float4*)(src + p * 128 + c);
    qin[p][c] = f2bf(v4.x);
    qin[p][c + 1] = f2bf(v4.y);
    qin[p][c + 2] = f2bf(v4.z);
    qin[p][c + 3] = f2bf(v4.w);
  }
  if (tid < 64) {
    const float* P = params + ((size_t)b * NPIX + n0 + tid) * 16;
    float sd = P[0], se = P[1], sa = P[2];
    sigf[tid][0] = sd; sigf[tid][1] = se; sigf[tid][2] = sa;
    sigf[tid][3] = 1.0f / (sd + 1e-6f);
    sigf[tid][4] = 1.0f / (se + 1e-6f);
    sigf[tid][5] = 1.0f / (sa + 1e-6f);
  }
  __syncthreads();
  int wave = tid >> 6, l = tid & 63;
  int lr = l & 15, lk = l >> 4;
  f32x4 acc[8];
#pragma unroll
  for (int nt = 0; nt < 8; nt++) {
    int n = nt * 16 + lr;
    float wt[6];
#pragma unroll
    for (int c = 0; c < 6; c++) wt[c] = qs_w1f[(size_t)n * 134 + 128 + c];
    float bias = qs_b1[n];
#pragma unroll
    for (int r = 0; r < 4; r++) {
      int pl = wave * 16 + lk * 4 + r;
      float a = bias;
#pragma unroll
      for (int c = 0; c < 6; c++) a += wt[c] * sigf[pl][c];
      acc[nt][r] = a;
    }
  }
#pragma unroll
  for (int ks = 0; ks < 4; ks++) {
    short8 a = *(const short8*)&qin[wave * 16 + lr][ks * 32 + lk * 8];
#pragma unroll
    for (int nt = 0; nt < 8; nt++) {
      short8 bv = *(const short8*)(qsW1p + (size_t)(nt * 16 + lr) * 128 + ks * 32 + lk * 8);
      acc[nt] = __builtin_amdgcn_mfma_f32_16x16x32_bf16(a, bv, acc[nt], 0, 0, 0);
    }
  }
#pragma unroll
  for (int nt = 0; nt < 8; nt++)
#pragma unroll
    for (int r = 0; r < 4; r++)
      hq[wave * 16 + lk * 4 + r][nt * 16 + lr] = f2bf(geluf(acc[nt][r]));
  __syncthreads();
#pragma unroll
  for (int nt = 0; nt < 8; nt++) {
    float bias = qs_b2[nt * 16 + lr];
    acc[nt] = (f32x4){bias, bias, bias, bias};
  }
#pragma unroll
  for (int ks = 0; ks < 4; ks++) {
    short8 a = *(const short8*)&hq[wave * 16 + lr][ks * 32 + lk * 8];
#pragma unroll
    for (int nt = 0; nt < 8; nt++) {
      short8 bv = *(const short8*)(qsW2p + (size_t)(nt * 16 + lr) * 128 + ks * 32 + lk * 8);
      acc[nt] = __builtin_amdgcn_mfma_f32_16x16x32_bf16(a, bv, acc[nt], 0, 0, 0);
    }
  }
#pragma unroll
  for (int nt = 0; nt < 8; nt++) {
    int n = nt * 16 + lr;
#pragma unroll
    for (int r = 0; r < 4; r++) {
      int p = n0 + wave * 16 + lk * 4 + r;
      query[((size_t)b * NPIX + p) * 128 + n] = acc[nt][r];
    }
  }
}

// ---------------- K8: pack weights to bf16 ----------------
__global__ __launch_bounds__(256) void k_pack(
    const float* __restrict__ val_w, const float* __restrict__ w_v,
    const float* __restrict__ b_v, const float* __restrict__ val_b,
    const float* __restrict__ off_w, const float* __restrict__ off_b,
    const float* __restrict__ aw_w, const float* __restrict__ aw_b,
    const float* __restrict__ out_w, const float* __restrict__ qs_w1,
    const float* __restrict__ qs_w2, const float* __restrict__ rh_w1,
    const float* __restrict__ w_q, const float* __restrict__ w_o,
    unsigned short* __restrict__ wvv_bf, float* __restrict__ bvv,
    unsigned short* __restrict__ projW, float* __restrict__ projB,
    unsigned short* __restrict__ outW, unsigned short* __restrict__ qsW1p,
    unsigned short* __restrict__ qsW2p, unsigned short* __restrict__ rhW1p,
    unsigned short* __restrict__ wqp, unsigned short* __restrict__ woP) {
  int idx = blockIdx.x * 256 + threadIdx.x;
  if (idx < 16384) {
    int o = idx >> 7, c = idx & 127;
    float acc = 0.0f;
    for (int m = 0; m < 128; m++) acc += val_w[o * 128 + m] * w_v[m * 128 + c];
    wvv_bf[idx] = f2bf(acc);
  } else if (idx < 16512) {
    int o = idx - 16384;
    float acc = val_b[o];
    for (int m = 0; m < 128; m++) acc += val_w[o * 128 + m] * b_v[m];
    bvv[o] = acc;
  } else if (idx < 82048) {
    int j = idx - 16512;
    int r = j >> 7, c = j & 127;
    float w = (r < 320) ? off_w[r * 128 + c] : ((r < 480) ? aw_w[(r - 320) * 128 + c] : 0.0f);
    projW[j] = f2bf(w);
  } else if (idx < 82560) {
    int r = idx - 82048;
    projB[r] = (r < 320) ? off_b[r] : ((r < 480) ? aw_b[r - 320] : 0.0f);
  } else if (idx < 98944) {
    int j = idx - 82560;
    outW[j] = f2bf(out_w[j]);
  } else if (idx < 115328) {
    int j = idx - 98944;
    int r = j >> 7, c = j & 127;
    qsW1p[j] = f2bf(qs_w1[r * 134 + c]);
  } else if (idx < 131712) {
    int j = idx - 115328;
    qsW2p[j] = f2bf(qs_w2[j]);
  } else if (idx < 144000) {
    int j = idx - 131712;
    int r = j / 96, c = j - r * 96;
    rhW1p[j] = (c < 67) ? f2bf(rh_w1[r * 67 + c]) : 0;
  } else if (idx < 156288) {
    int j = idx - 144000;
    int r = j / 96, c = j - r * 96;
    wqp[j] = (c < 64) ? f2bf(w_q[r * 64 + c]) : 0;
  } else if (idx < 172672) {
    int j = idx - 156288;
    woP[j] = f2bf(w_o[j]);
  }
}

// ---------------- K9: MFMA value projection v[b,p,o] = Wvv@bev + bvv (bf16 out) ----------------
__global__ __launch_bounds__(256) void k_value(
    const float* __restrict__ bev, const unsigned short* __restrict__ wvv_bf,
    const float* __restrict__ bvv, unsigned short* __restrict__ v) {
  __shared__ float lds[128 * 66];
  int b = blockIdx.y;
  int p0 = blockIdx.x * 64;
  int tid = threadIdx.x;
  int npx = NBEV - p0; if (npx > 64) npx = 64;
  for (int i = tid; i < 128 * 64; i += 256) {
    int c = i >> 6, p = i & 63;
    lds[c * 66 + p] = (p < npx) ? bev[((size_t)b * 128 + c) * NBEV + p0 + p] : 0.0f;
  }
  __syncthreads();
  int wave = tid >> 6, l = tid & 63;
  int lr = l & 15, lk = l >> 4;
  int ploc = wave * 16 + lr;
  f32x4 acc[8];
#pragma unroll
  for (int nt = 0; nt < 8; nt++) {
    float bias = bvv[nt * 16 + lr];
    acc[nt] = (f32x4){bias, bias, bias, bias};
  }
#pragma unroll
  for (int ks = 0; ks < 4; ks++) {
    int k0 = ks * 32 + lk * 8;
    short8 a;
#pragma unroll
    for (int j = 0; j < 8; j++) a[j] = (short)f2bf(lds[(k0 + j) * 66 + ploc]);
#pragma unroll
    for (int nt = 0; nt < 8; nt++) {
      short8 bf = *(const short8*)(wvv_bf + (size_t)(nt * 16 + lr) * 128 + k0);
      acc[nt] = __builtin_amdgcn_mfma_f32_16x16x32_bf16(a, bf, acc[nt], 0, 0, 0);
    }
  }
#pragma unroll
  for (int nt = 0; nt < 8; nt++) {
    int n = nt * 16 + lr;
#pragma unroll
    for (int r = 0; r < 4; r++) {
      int p = p0 + wave * 16 + lk * 4 + r;
      if (p < NBEV) v[((size_t)b * NBEV + p) * 128 + n] = f2bf(acc[nt][r]);
    }
  }
}

// ---------------- K10: MFMA projection (query -> 512 outs, bf16) ----------------
__global__ __launch_bounds__(256) void k_proj(
    const float* __restrict__ query, const unsigned short* __restrict__ projW,
    const float* __restrict__ projB, unsigned short* __restrict__ proj) {
  int b = blockIdx.z;
  int wave = threadIdx.x >> 6, l = threadIdx.x & 63;
  int lr = l & 15, lk = l >> 4;
  int p0 = blockIdx.x * 64 + wave * 16;
  int n0 = blockIdx.y * 128;
  f32x4 acc[8];
#pragma unroll
  for (int nt = 0; nt < 8; nt++) {
    float bias = projB[n0 + nt * 16 + lr];
    acc[nt] = (f32x4){bias, bias, bias, bias};
  }
  const float* ap = query + ((size_t)b * NPIX + p0 + lr) * 128 + lk * 8;
#pragma unroll
  for (int ks = 0; ks < 4; ks++) {
    float4 a0 = *(const float4*)(ap + ks * 32);
    float4 a1 = *(const float4*)(ap + ks * 32 + 4);
    short8 a;
    a[0] = (short)f2bf(a0.x); a[1] = (short)f2bf(a0.y);
    a[2] = (short)f2bf(a0.z); a[3] = (short)f2bf(a0.w);
    a[4] = (short)f2bf(a1.x); a[5] = (short)f2bf(a1.y);
    a[6] = (short)f2bf(a1.z); a[7] = (short)f2bf(a1.w);
#pragma unroll
    for (int nt = 0; nt < 8; nt++) {
      short8 bf = *(const short8*)(projW + (size_t)(n0 + nt * 16 + lr) * 128 + ks * 32 + lk * 8);
      acc[nt] = __builtin_amdgcn_mfma_f32_16x16x32_bf16(a, bf, acc[nt], 0, 0, 0);
    }
  }
#pragma unroll
  for (int nt = 0; nt < 8; nt++) {
    int n = n0 + nt * 16 + lr;
#pragma unroll
    for (int r = 0; r < 4; r++) {
      int p = p0 + lk * 4 + r;
      proj[((size_t)b * NPIX + p) * 512 + n] = f2bf(acc[nt][r]);
    }
  }
}

// ---------------- K11: sampler (4 threads per (pixel,head)) ----------------
__global__ __launch_bounds__(256) void k_samp(
    const unsigned short* __restrict__ proj, const float* __restrict__ params,
    const unsigned short* __restrict__ v, unsigned short* __restrict__ S) {
  int b = blockIdx.y;
  int bid = blockIdx.x;
  int pb = (bid & 7) * 256 + (bid >> 3);  // XCD-chunked swizzle
  int tid = threadIdx.x;
  int q = tid & 3, hh = (tid >> 2) & 7, pl = tid >> 5;
  int n = pb * 8 + pl;
  const unsigned short* base = proj + ((size_t)b * NPIX + n) * 512;
  float mx = -1e30f;
#pragma unroll
  for (int i = 0; i < 20; i++) mx = fmaxf(mx, bf2f(base[320 + hh * 20 + i]));
  float s = 0.0f;
#pragma unroll
  for (int i = 0; i < 20; i++) s += expf(bf2f(base[320 + hh * 20 + i]) - mx);
  float rs = 1.0f / s;
  const float* P = params + ((size_t)b * NPIX + n) * 16;
  const unsigned short* vb = v + (size_t)b * NBEV * 128 + hh * 16 + q * 4;
  float ac0 = 0.f, ac1 = 0.f, ac2 = 0.f, ac3 = 0.f;
  for (int kp = 0; kp < 20; kp++) {
    int k = kp >> 2, pp = kp & 3;
    float lx = P[3 + 2 * k] + bf2f(base[hh * 40 + k * 8 + pp * 2 + 0]) * (1.0f / 220.0f);
    float ly = P[4 + 2 * k] + bf2f(base[hh * 40 + k * 8 + pp * 2 + 1]) * (1.0f / 220.0f);
    float a = expf(bf2f(base[320 + hh * 20 + kp]) - mx) * rs;
    float X = lx * 220.0f - 0.5f;
    float Y = ly * 220.0f - 0.5f;
    float xf = floorf(X), yf = floorf(Y);
    float wx = X - xf, wy = Y - yf;
    int x0 = (int)xf, y0 = (int)yf;
#pragma unroll
    for (int dy = 0; dy < 2; dy++) {
      int yi = y0 + dy;
      if (yi < 0 || yi >= 220) continue;
      float wyv = dy ? wy : (1.0f - wy);
#pragma unroll
      for (int dx = 0; dx < 2; dx++) {
        int xi = x0 + dx;
        if (xi < 0 || xi >= 220) continue;
        float wgt = a * wyv * (dx ? wx : (1.0f - wx));
        uint2 raw = *(const uint2*)(vb + (size_t)(yi * 220 + xi) * 128);
        ac0 += wgt * bf2f((unsigned short)(raw.x & 0xffffu));
        ac1 += wgt * bf2f((unsigned short)(raw.x >> 16));
        ac2 += wgt * bf2f((unsigned short)(raw.y & 0xffffu));
        ac3 += wgt * bf2f((unsigned short)(raw.y >> 16));
      }
    }
  }
  uint2 outp;
  outp.x = (unsigned int)f2bf(ac0) | ((unsigned int)f2bf(ac1) << 16);
  outp.y = (unsigned int)f2bf(ac2) | ((unsigned int)f2bf(ac3) << 16);
  *(uint2*)(S + ((size_t)b * NPIX + n) * 128 + hh * 16 + q * 4) = outp;
}

// ---------------- K12: MFMA out-projection + residual -> ymsda f32 ----------------
__global__ __launch_bounds__(256) void k_out(
    const unsigned short* __restrict__ S, const unsigned short* __restrict__ outW,
    const float* __restrict__ out_b, const float* __restrict__ query,
    float* __restrict__ ymsda) {
  int b = blockIdx.y;
  int wave = threadIdx.x >> 6, l = threadIdx.x & 63;
  int lr = l & 15, lk = l >> 4;
  int p0 = blockIdx.x * 64 + wave * 16;
  f32x4 acc[8];
#pragma unroll
  for (int nt = 0; nt < 8; nt++) {
    float bias = out_b[nt * 16 + lr];
    acc[nt] = (f32x4){bias, bias, bias, bias};
  }
  const unsigned short* ap = S + ((size_t)b * NPIX + p0 + lr) * 128 + lk * 8;
#pragma unroll
  for (int ks = 0; ks < 4; ks++) {
    short8 a = *(const short8*)(ap + ks * 32);
#pragma unroll
    for (int nt = 0; nt < 8; nt++) {
      short8 bf = *(const short8*)(outW + (size_t)(nt * 16 + lr) * 128 + ks * 32 + lk * 8);
      acc[nt] = __builtin_amdgcn_mfma_f32_16x16x32_bf16(a, bf, acc[nt], 0, 0, 0);
    }
  }
#pragma unroll
  for (int nt = 0; nt < 8; nt++) {
    int n = nt * 16 + lr;
#pragma unroll
    for (int r = 0; r < 4; r++) {
      int p = p0 + lk * 4 + r;
      size_t o = ((size_t)b * NPIX + p) * 128 + n;
      ymsda[o] = acc[nt][r] + query[o];
    }
  }
}

// ---------------- K13: MFMA final conv1x1 + LDS-transposed NCHW store ----------------
__global__ __launch_bounds__(256) void k_final(
    const float* __restrict__ ymsda, const unsigned short* __restrict__ woP,
    const float* __restrict__ b_o, float* __restrict__ out) {
  __shared__ float yt[128][67];
  int b = blockIdx.y;
  int p0 = blockIdx.x * 64;
  int tid = threadIdx.x;
  int wave = tid >> 6, l = tid & 63;
  int lr = l & 15, lk = l >> 4;
  f32x4 acc[8];
#pragma unroll
  for (int nt = 0; nt < 8; nt++) {
    float bias = b_o[nt * 16 + lr];
    acc[nt] = (f32x4){bias, bias, bias, bias};
  }
  const float* ap = ymsda + ((size_t)b * NPIX + p0 + wave * 16 + lr) * 128 + lk * 8;
#pragma unroll
  for (int ks = 0; ks < 4; ks++) {
    float4 a0 = *(const float4*)(ap + ks * 32);
    float4 a1 = *(const float4*)(ap + ks * 32 + 4);
    short8 a;
    a[0] = (short)f2bf(a0.x); a[1] = (short)f2bf(a0.y);
    a[2] = (short)f2bf(a0.z); a[3] = (short)f2bf(a0.w);
    a[4] = (short)f2bf(a1.x); a[5] = (short)f2bf(a1.y);
    a[6] = (short)f2bf(a1.z); a[7] = (short)f2bf(a1.w);
#pragma unroll
    for (int nt = 0; nt < 8; nt++) {
      short8 bf = *(const short8*)(woP + (size_t)(nt * 16 + lr) * 128 + ks * 32 + lk * 8);
      acc[nt] = __builtin_amdgcn_mfma_f32_16x16x32_bf16(a, bf, acc[nt], 0, 0, 0);
    }
  }
#pragma unroll
  for (int nt = 0; nt < 8; nt++)
#pragma unroll
    for (int r = 0; r < 4; r++)
      yt[nt * 16 + lr][wave * 16 + lk * 4 + r] = acc[nt][r];
  __syncthreads();
  int n = tid >> 1, half = tid & 1;
  float* dst = out + ((size_t)(b * 128 + n)) * NPIX + p0 + half * 32;
#pragma unroll
  for (int j = 0; j < 8; j++) {
    float4 v4 = {yt[n][half * 32 + j * 4], yt[n][half * 32 + j * 4 + 1],
                 yt[n][half * 32 + j * 4 + 2], yt[n][half * 32 + j * 4 + 3]};
    *(float4*)(dst + j * 4) = v4;
  }
}

__global__ void k_klfin(const float* __restrict__ klpart, float* __restrict__ out) {
  if (threadIdx.x == 0) {
    float s = 0.0f;
    for (int i = 0; i < 128; i++) s += klpart[i];
    out[(size_t)BSZ * 128 * NPIX] = 1e-4f * (s / 32768.0f);
  }
}

// ---------------- host ----------------
static RVConsts make_consts() {
  static const float ELEV[32] = {
      -30.67f, -29.33f, -28.0f, -26.66f, -25.33f, -24.0f, -22.67f, -21.33f,
      -20.0f,  -18.67f, -17.33f, -16.0f, -14.67f, -13.33f, -12.0f, -10.67f,
      -9.33f,  -8.0f,   -6.66f,  -5.33f, -4.0f,   -2.67f,  -1.33f, 0.0f,
      1.33f,   2.67f,   4.0f,    5.33f,  6.67f,   8.0f,    9.33f,  10.67f};
  RVConsts C;
  const float d2r = 0.017453292519943295f;
  for (int r = 0; r < 16; r++) {
    float a = ELEV[31 - 2 * r], b = ELEV[30 - 2 * r];
    float mx = fmaxf(a, b), mn = fminf(a, b);
    C.steps[r] = (mx - mn) * d2r;
    C.means[r] = ((a + b) * 0.5f) * d2r;
  }
  const double PI_D = 3.14159265358979323846;
  double step_d = (PI_D - (-PI_D)) / 1024.0;
  double az0 = -PI_D;
  double az1 = az0 + step_d;
  double az_step_d = az1 - az0;
  C.az_step_f = (float)az_step_d;
  C.pad_ = 0.0f;
  C.step_d = step_d;
  C.az0 = az0;
  C.az_half = az_step_d * 0.5;
  return C;
}

// Workspace layout (f32 words). Peak 21,583,744 words = 86.3 MB.
#define OFF_T1     0u          /* 4,194,304 ; later overlaid by proj_bf then ymsda */
#define OFF_H1     4194304u    /* 4,194,304 ; later overlaid by proj_bf */
#define OFF_T2     8388608u    /* 2,097,152 ; later overlaid by v_bf */
#define OFF_Q0     10485760u   /* 4,194,304 ; later overlaid by v_bf */
#define OFF_PARAMS 14680064u   /* 524,288 */
#define OFF_QUERY  15204352u   /* 4,194,304 */
#define OFF_S      19398656u   /* 2,097,152 (bf16 x 4,194,304) */
#define OFF_SUMS1  21495808u
#define OFF_SUMS2  21496320u
#define OFF_STATS1 21496832u
#define OFF_STATS2 21496864u
#define OFF_KL     21496896u
#define OFF_PROJ   0u          /* bf16 x 16,777,216 (after conv3; t1/h1 dead) */
#define OFF_V      8388608u    /* bf16 x 12,390,400 (after head+query; t2/q0 dead) */
#define OFF_YMSDA  0u          /* f32 x 4,194,304 (after samp consumes proj) */
/* prepacked weights: dedicated top region, never overlaid */
#define OFF_WVV    21497088u   /* bf16 x 16384 -> 8192 w */
#define OFF_BVV    21505280u   /* f32 x 128 */
#define OFF_PROJW  21505408u   /* bf16 x 65536 -> 32768 w */
#define OFF_PROJB  21538176u   /* f32 x 512 */
#define OFF_OUTW   21538688u   /* bf16 x 16384 -> 8192 w */
#define OFF_QSW1   21546880u   /* bf16 x 16384 -> 8192 w */
#define OFF_QSW2   21555072u   /* bf16 x 16384 -> 8192 w */
#define OFF_RHW1   21563264u   /* bf16 x 12288 -> 6144 w */
#define OFF_WQP    21569408u   /* bf16 x 12288 -> 6144 w */
#define OFF_WOP    21575552u   /* bf16 x 16384 -> 8192 w */

extern "C" void kernel_launch(void* const* d_in, const int* in_sizes, int n_in,
                              void* d_out, int out_size, void* d_ws, size_t ws_size,
                              hipStream_t stream) {
  const float* x_rv = (const float*)d_in[0];
  const float* bev = (const float*)d_in[1];
  const float* l2e = (const float*)d_in[2];
  const float* w_q = (const float*)d_in[3];
  const float* b_q = (const float*)d_in[4];
  const float* w_v = (const float*)d_in[5];
  const float* b_v = (const float*)d_in[6];
  const float* w_o = (const float*)d_in[7];
  const float* b_o = (const float*)d_in[8];
  const float* qs_w1 = (const float*)d_in[9];
  const float* qs_b1 = (const float*)d_in[10];
  const float* qs_w2 = (const float*)d_in[11];
  const float* qs_b2 = (const float*)d_in[12];
  const float* rh_w1 = (const float*)d_in[13];
  const float* rh_b1 = (const float*)d_in[14];
  const float* rh_g1 = (const float*)d_in[15];
  const float* rh_bt1 = (const float*)d_in[16];
  const float* rh_w2 = (const float*)d_in[17];
  const float* rh_g2 = (const float*)d_in[18];
  const float* rh_bt2 = (const float*)d_in[19];
  const float* rh_w3 = (const float*)d_in[20];
  const float* rh_b3 = (const float*)d_in[21];
  const float* off_w = (const float*)d_in[22];
  const float* off_b = (const float*)d_in[23];
  const float* aw_w = (const float*)d_in[24];
  const float* aw_b = (const float*)d_in[25];
  const float* val_w = (const float*)d_in[26];
  const float* val_b = (const float*)d_in[27];
  const float* out_w = (const float*)d_in[28];
  const float* out_b = (const float*)d_in[29];

  float* ws = (float*)d_ws;
  float* t1 = ws + OFF_T1;
  float* h1 = ws + OFF_H1;
  float* t2 = ws + OFF_T2;
  float* q0 = ws + OFF_Q0;
  float* params = ws + OFF_PARAMS;
  float* query = ws + OFF_QUERY;
  float* sums1 = ws + OFF_SUMS1;
  float* sums2 = ws + OFF_SUMS2;
  float* stats1 = ws + OFF_STATS1;
  float* stats2 = ws + OFF_STATS2;
  float* klpart = ws + OFF_KL;
  float* bvv = ws + OFF_BVV;
  float* projB = ws + OFF_PROJB;
  float* ymsda = ws + OFF_YMSDA;
  unsigned short* S_bf = (unsigned short*)(ws + OFF_S);
  unsigned short* proj_bf = (unsigned short*)(ws + OFF_PROJ);
  unsigned short* v_bf = (unsigned short*)(ws + OFF_V);
  unsigned short* wvv_bf = (unsigned short*)(ws + OFF_WVV);
  unsigned short* projW = (unsigned short*)(ws + OFF_PROJW);
  unsigned short* outW = (unsigned short*)(ws + OFF_OUTW);
  unsigned short* qsW1p = (unsigned short*)(ws + OFF_QSW1);
  unsigned short* qsW2p = (unsigned short*)(ws + OFF_QSW2);
  unsigned short* rhW1p = (unsigned short*)(ws + OFF_RHW1);
  unsigned short* wqp = (unsigned short*)(ws + OFF_WQP);
  unsigned short* woP = (unsigned short*)(ws + OFF_WOP);

  RVConsts C = make_consts();
  dim3 blk(256);

  k_pack<<<675, blk, 0, stream>>>(val_w, w_v, b_v, val_b, off_w, off_b, aw_w, aw_b, out_w,
                                  qs_w1, qs_w2, rh_w1, w_q, w_o,
                                  wvv_bf, bvv, projW, projB, outW, qsW1p, qsW2p, rhW1p,
                                  wqp, woP);
  k_rh1_q0<<<dim3(256, BSZ), blk, 0, stream>>>(x_rv, rhW1p, rh_b1, wqp, b_q, t1, q0, C);
  k_gnsum<128, 16><<<dim3(16, 8, BSZ), blk, 0, stream>>>(t1, sums1);
  k_gnfin<<<1, 64, 0, stream>>>(sums1, stats1, 1.0f / 262144.0f);
  k_gn1_gelu<<<16384, blk, 0, stream>>>(t1, stats1, rh_g1, rh_bt1, h1);
  k_conv3<<<dim3(1024, BSZ), blk, 0, stream>>>(h1, rh_w2, t2);
  k_gnsum<64, 8><<<dim3(16, 8, BSZ), blk, 0, stream>>>(t2, sums2);
  k_gnfin<<<1, 64, 0, stream>>>(sums2, stats2, 1.0f / 131072.0f);
  k_head<<<dim3(64, BSZ), blk, 0, stream>>>(t2, stats2, rh_g2, rh_bt2, rh_w3, rh_b3,
                                            l2e, params, klpart, C);
  k_query<<<dim3(256, BSZ), blk, 0, stream>>>(q0, params, qsW1p, qs_b1, qs_w1, qsW2p,
                                              qs_b2, query);
  k_value<<<dim3(757, BSZ), blk, 0, stream>>>(bev, wvv_bf, bvv, v_bf);
  k_proj<<<dim3(256, 4, BSZ), blk, 0, stream>>>(query, projW, projB, proj_bf);
  k_samp<<<dim3(2048, BSZ), blk, 0, stream>>>(proj_bf, params, v_bf, S_bf);
  k_out<<<dim3(256, BSZ), blk, 0, stream>>>(S_bf, outW, out_b, query, ymsda);
  k_final<<<dim3(256, BSZ), blk, 0, stream>>>(ymsda, woP, b_o, (float*)d_out);
  k_klfin<<<1, 64, 0, stream>>>(klpart, (float*)d_out);
}

// Round 5
// 364.503 us; speedup vs baseline: 3.9445x; 1.2052x over previous
//
#include <hip/hip_runtime.h>
#include <math.h>

#define HRV 16
#define WRV 1024
#define NPIX 16384
#define NBEV 48400
#define BSZ 2

typedef __attribute__((ext_vector_type(8))) short short8;
typedef __attribute__((ext_vector_type(4))) float f32x4;

struct RVConsts {
  float steps[16];
  float means[16];
  float az_step_f;
  float pad_;
  double step_d;
  double az0;
  double az_half;
};

__device__ __forceinline__ float geluf(float x) {
  return 0.5f * x * (1.0f + erff(x * 0.70710678118654752440f));
}
__device__ __forceinline__ float sigmoidf_(float x) {
  return 1.0f / (1.0f + expf(-x));
}
__device__ __forceinline__ float softplusf_(float x) {
  return fmaxf(x, 0.0f) + log1pf(expf(-fabsf(x)));
}
__device__ __forceinline__ float azimf(int w, double step_d, double az0, double az_half) {
  double az = (double)w * step_d + az0;
  az += az_half;
  return (float)az;
}
__device__ __forceinline__ unsigned short f2bf(float f) {
  unsigned int u = __builtin_bit_cast(unsigned int, f);
  u = u + 0x7FFFu + ((u >> 16) & 1u);
  return (unsigned short)(u >> 16);
}
__device__ __forceinline__ float bf2f(unsigned short h) {
  unsigned int u = ((unsigned int)h) << 16;
  return __builtin_bit_cast(float, u);
}

// ---------------- K1: MFMA range-head conv1 (67->128) + Q0 conv (64->128) ----------------
__global__ __launch_bounds__(256) void k_rh1_q0(
    const float* __restrict__ x_rv,
    const unsigned short* __restrict__ rhW1p, const float* __restrict__ rh_b1,
    const unsigned short* __restrict__ wqp, const float* __restrict__ b_q,
    float* __restrict__ t1, float* __restrict__ q0, RVConsts C) {
  __shared__ unsigned short xin[64][104];
  int b = blockIdx.y;
  int n0 = blockIdx.x * 64;
  int tid = threadIdx.x;
  const float* src = x_rv + ((size_t)b * NPIX + n0) * 64;
  for (int i = tid; i < 1024; i += 256) {
    int p = i >> 4, c = (i & 15) * 4;
    float4 v4 = *(const float4*)(src + p * 64 + c);
    xin[p][c] = f2bf(v4.x);
    xin[p][c + 1] = f2bf(v4.y);
    xin[p][c + 2] = f2bf(v4.z);
    xin[p][c + 3] = f2bf(v4.w);
  }
  if (tid < 64) {
    int n = n0 + tid;
    int h = n >> 10, w = n & 1023;
    float E = C.means[h];
    float A = azimf(w, C.step_d, C.az0, C.az_half);
    float ce = cosf(E);
    xin[tid][64] = f2bf(ce * cosf(A));
    xin[tid][65] = f2bf(ce * sinf(A));
    xin[tid][66] = f2bf(sinf(E));
    for (int c = 67; c < 104; c++) xin[tid][c] = 0;
  }
  __syncthreads();
  int wave = tid >> 6, l = tid & 63;
  int lr = l & 15, lk = l >> 4;
  f32x4 acc[8], accq[8];
#pragma unroll
  for (int nt = 0; nt < 8; nt++) {
    float b1 = rh_b1[nt * 16 + lr], b2 = b_q[nt * 16 + lr];
    acc[nt] = (f32x4){b1, b1, b1, b1};
    accq[nt] = (f32x4){b2, b2, b2, b2};
  }
#pragma unroll
  for (int ks = 0; ks < 3; ks++) {
    short8 a = *(const short8*)&xin[wave * 16 + lr][ks * 32 + lk * 8];
#pragma unroll
    for (int nt = 0; nt < 8; nt++) {
      short8 b1v = *(const short8*)(rhW1p + (size_t)(nt * 16 + lr) * 96 + ks * 32 + lk * 8);
      acc[nt] = __builtin_amdgcn_mfma_f32_16x16x32_bf16(a, b1v, acc[nt], 0, 0, 0);
      short8 b2v = *(const short8*)(wqp + (size_t)(nt * 16 + lr) * 96 + ks * 32 + lk * 8);
      accq[nt] = __builtin_amdgcn_mfma_f32_16x16x32_bf16(a, b2v, accq[nt], 0, 0, 0);
    }
  }
#pragma unroll
  for (int nt = 0; nt < 8; nt++) {
    int n = nt * 16 + lr;
#pragma unroll
    for (int r = 0; r < 4; r++) {
      int p = n0 + wave * 16 + lk * 4 + r;
      size_t o = ((size_t)b * NPIX + p) * 128 + n;
      t1[o] = acc[nt][r];
      q0[o] = accq[nt][r];
    }
  }
}

// ---------------- GroupNorm partial sums ----------------
template <int CCH, int CGRP>
__global__ __launch_bounds__(256) void k_gnsum(const float* __restrict__ src,
                                               float* __restrict__ sums) {
  int chunk = blockIdx.x;
  int g = blockIdx.y;
  int b = blockIdx.z;
  const int npx = NPIX / 16;
  int n0 = chunk * npx;
  int tid = threadIdx.x;
  float s = 0.f, ss = 0.f;
  const float* base = src + (size_t)b * NPIX * CCH + (size_t)g * CGRP;
  const int total = npx * CGRP;
  for (int i = tid; i < total; i += 256) {
    int n = i / CGRP;
    int cc = i % CGRP;
    float x = base[(size_t)(n0 + n) * CCH + cc];
    s += x; ss += x * x;
  }
#pragma unroll
  for (int o2 = 32; o2 > 0; o2 >>= 1) { s += __shfl_down(s, o2); ss += __shfl_down(ss, o2); }
  __shared__ float wsum[4][2];
  if ((tid & 63) == 0) { wsum[tid >> 6][0] = s; wsum[tid >> 6][1] = ss; }
  __syncthreads();
  if (tid == 0) {
    float S = wsum[0][0] + wsum[1][0] + wsum[2][0] + wsum[3][0];
    float SS = wsum[0][1] + wsum[1][1] + wsum[2][1] + wsum[3][1];
    sums[((b * 8 + g) * 16 + chunk) * 2 + 0] = S;
    sums[((b * 8 + g) * 16 + chunk) * 2 + 1] = SS;
  }
}

__global__ void k_gnfin(const float* __restrict__ sums, float* __restrict__ stats, float invN) {
  int i = threadIdx.x;
  if (i >= 16) return;
  float S = 0.f, SS = 0.f;
  for (int ch = 0; ch < 16; ch++) { S += sums[(i * 16 + ch) * 2]; SS += sums[(i * 16 + ch) * 2 + 1]; }
  float m = S * invN;
  float var = SS * invN - m * m;
  stats[i * 2] = m;
  stats[i * 2 + 1] = rsqrtf(var + 1e-5f);
}

// ---------------- K3: apply GN1 + GELU -> bf16 h1 ----------------
__global__ __launch_bounds__(256) void k_gn1_gelu(
    const float* __restrict__ t1, const float* __restrict__ stats1,
    const float* __restrict__ g1, const float* __restrict__ bt1,
    unsigned short* __restrict__ h1) {
  size_t i4 = ((size_t)blockIdx.x * 256 + threadIdx.x) * 4;
  int c = (int)(i4 & 127);
  int bidx = (int)(i4 >> 21);
  int g = c >> 4;
  float m = stats1[(bidx * 8 + g) * 2], is = stats1[(bidx * 8 + g) * 2 + 1];
  float4 x4 = *(const float4*)(t1 + i4);
  float y0 = geluf((x4.x - m) * is * g1[c] + bt1[c]);
  float y1 = geluf((x4.y - m) * is * g1[c + 1] + bt1[c + 1]);
  float y2 = geluf((x4.z - m) * is * g1[c + 2] + bt1[c + 2]);
  float y3 = geluf((x4.w - m) * is * g1[c + 3] + bt1[c + 3]);
  uint2 o;
  o.x = (unsigned int)f2bf(y0) | ((unsigned int)f2bf(y1) << 16);
  o.y = (unsigned int)f2bf(y2) | ((unsigned int)f2bf(y3) << 16);
  *(uint2*)(h1 + i4) = o;
}

// ---------------- K4: MFMA 3x3 circular conv (128 -> 64), 9 shifted GEMMs ----------------
// LDS: [3 rows][66 w][128 c] bf16, XOR-swizzled (byte ^= ((rw&7)<<4)); 16B granularity preserved.
__device__ __forceinline__ int cswz(int rw, int c) {
  int byte = (rw << 8) + (c << 1);
  return byte ^ ((rw & 7) << 4);
}
__global__ __launch_bounds__(256) void k_conv3(const unsigned short* __restrict__ h1,
                                               const unsigned short* __restrict__ w2p,
                                               float* __restrict__ t2) {
  __shared__ unsigned short tile[3 * 66 * 128];  // 50688 B
  int b = blockIdx.y;
  int n0 = blockIdx.x * 64;
  int h = n0 >> 10;
  int w0 = n0 & 1023;
  int tid = threadIdx.x;
  // stage: 3 rows x 66 w x 128 c; 8 bf16 (16B) per thread-iter
  for (int i = tid; i < 3 * 66 * 16; i += 256) {
    int r = i / (66 * 16);
    int rem = i - r * 66 * 16;
    int w = rem >> 4;
    int c0 = (rem & 15) * 8;
    int hh = (h + r - 1 + HRV) & (HRV - 1);
    int wc = (w0 + w - 1 + WRV) & (WRV - 1);
    uint4 v = *(const uint4*)(h1 + ((size_t)b * NPIX + hh * WRV + wc) * 128 + c0);
    *(uint4*)((char*)tile + cswz(r * 66 + w, c0)) = v;
  }
  __syncthreads();
  int wave = tid >> 6, l = tid & 63;
  int lr = l & 15, lk = l >> 4;
  f32x4 acc[4];
#pragma unroll
  for (int nt = 0; nt < 4; nt++) acc[nt] = (f32x4){0.f, 0.f, 0.f, 0.f};
#pragma unroll
  for (int kpos = 0; kpos < 9; kpos++) {
    int ky = kpos / 3, kx = kpos - ky * 3;
    int rw = ky * 66 + wave * 16 + lr + kx;
#pragma unroll
    for (int ks = 0; ks < 4; ks++) {
      short8 a = *(const short8*)((const char*)tile + cswz(rw, ks * 32 + lk * 8));
#pragma unroll
      for (int nt = 0; nt < 4; nt++) {
        short8 bv = *(const short8*)(w2p + (size_t)(kpos * 64 + nt * 16 + lr) * 128 +
                                     ks * 32 + lk * 8);
        acc[nt] = __builtin_amdgcn_mfma_f32_16x16x32_bf16(a, bv, acc[nt], 0, 0, 0);
      }
    }
  }
#pragma unroll
  for (int nt = 0; nt < 4; nt++) {
    int o = nt * 16 + lr;
#pragma unroll
    for (int r = 0; r < 4; r++) {
      int p = n0 + wave * 16 + lk * 4 + r;
      t2[((size_t)b * NPIX + p) * 64 + o] = acc[nt][r];
    }
  }
}

// ---------------- K6: GN2+GELU -> head(4) -> params + KL ----------------
__global__ __launch_bounds__(256) void k_head(
    const float* __restrict__ t2, const float* __restrict__ stats2,
    const float* __restrict__ g2, const float* __restrict__ bt2,
    const float* __restrict__ rh_w3, const float* __restrict__ rh_b3,
    const float* __restrict__ l2e, float* __restrict__ params,
    float* __restrict__ klpart, RVConsts C) {
  int b = blockIdx.y;
  int n = blockIdx.x * 256 + threadIdx.x;
  int h = n >> 10, w = n & 1023;
  const float* t = t2 + ((size_t)b * NPIX + n) * 64;
  float hd0 = rh_b3[0], hd1 = rh_b3[1], hd2 = rh_b3[2], hd3 = rh_b3[3];
  for (int c = 0; c < 64; c++) {
    int g = c >> 3;
    float m = stats2[(b * 8 + g) * 2], is = stats2[(b * 8 + g) * 2 + 1];
    float xv = geluf((t[c] - m) * is * g2[c] + bt2[c]);
    hd0 += rh_w3[c] * xv;
    hd1 += rh_w3[64 + c] * xv;
    hd2 += rh_w3[128 + c] * xv;
    hd3 += rh_w3[192 + c] * xv;
  }
  float mu = sigmoidf_(hd0) * 55.0f;
  float sd = softplusf_(hd1) + 1e-3f;
  float stepw = C.steps[w & 15];
  float se = sigmoidf_(hd2) * stepw + 1e-3f;
  float sa = sigmoidf_(hd3) * C.az_step_f + 1e-3f;
  float E0 = C.means[h];
  float A0 = azimf(w, C.step_d, C.az0, C.az_half);
  float* P = params + ((size_t)b * NPIX + n) * 16;
  P[0] = sd; P[1] = se; P[2] = sa;
  float M00 = l2e[0], M01 = l2e[1], M10 = l2e[4], M11 = l2e[5];
  float M20 = l2e[8], M21 = l2e[9], M30 = l2e[12], M31 = l2e[13];
#pragma unroll
  for (int k = 0; k < 5; k++) {
    float off = -0.6f + 0.3f * (float)k;
    float d = mu + sd * off;
    float E = E0 + se * off;
    float A = A0 + sa * off;
    float ce = cosf(E);
    float xl = d * ce * cosf(A), yl = d * ce * sinf(A), zl = d * sinf(E);
    float px = xl * M00 + yl * M10 + zl * M20 + M30;
    float py = xl * M01 + yl * M11 + zl * M21 + M31;
    P[3 + 2 * k] = sigmoidf_(4.0f * ((px + 55.0f) * (1.0f / 110.0f) - 0.5f));
    P[4 + 2 * k] = sigmoidf_(4.0f * ((py + 55.0f) * (1.0f / 110.0f) - 0.5f));
  }
  float mu_n = mu * (1.0f / 55.0f);
  float sr = fmaxf(sd, 1e-6f);
  float saz = sa / C.az_step_f;
  float sel = se / stepw;
  float L = 0.5f * (mu_n * mu_n + sr * sr - logf(sr * sr) - 1.0f) +
            0.5f * (saz * saz - logf(saz * saz) - 1.0f) +
            0.5f * (sel * sel - logf(sel * sel) - 1.0f);
#pragma unroll
  for (int o2 = 32; o2 > 0; o2 >>= 1) L += __shfl_down(L, o2);
  __shared__ float wsum[4];
  if ((threadIdx.x & 63) == 0) wsum[threadIdx.x >> 6] = L;
  __syncthreads();
  if (threadIdx.x == 0)
    klpart[blockIdx.y * 64 + blockIdx.x] = wsum[0] + wsum[1] + wsum[2] + wsum[3];
}

// ---------------- K7: MFMA query MLP ----------------
__global__ __launch_bounds__(256) void k_query(
    const float* __restrict__ q0, const float* __restrict__ params,
    const unsigned short* __restrict__ qsW1p, const float* __restrict__ qs_b1,
    const float* __restrict__ qs_w1f,
    const unsigned short* __restrict__ qsW2p, const float* __restrict__ qs_b2,
    float* __restrict__ query) {
  __shared__ unsigned short qin[64][136];
  __shared__ unsigned short hq[64][136];
  __shared__ float sigf[64][6];
  int b = blockIdx.y;
  int n0 = blockIdx.x * 64;
  int tid = threadIdx.x;
  const float* src = q0 + ((size_t)b * NPIX + n0) * 128;
  for (int i = tid; i < 2048; i += 256) {
    int p = i >> 5, c = (i & 31) * 4;
    float4 v4 = *(const float4*)(src + p * 128 + c);
    qin[p][c] = f2bf(v4.x);
    qin[p][c + 1] = f2bf(v4.y);
    qin[p][c + 2] = f2bf(v4.z);
    qin[p][c + 3] = f2bf(v4.w);
  }
  if (tid < 64) {
    const float* P = params + ((size_t)b * NPIX + n0 + tid) * 16;
    float sd = P[0], se = P[1], sa = P[2];
    sigf[tid][0] = sd; sigf[tid][1] = se; sigf[tid][2] = sa;
    sigf[tid][3] = 1.0f / (sd + 1e-6f);
    sigf[tid][4] = 1.0f / (se + 1e-6f);
    sigf[tid][5] = 1.0f / (sa + 1e-6f);
  }
  __syncthreads();
  int wave = tid >> 6, l = tid & 63;
  int lr = l & 15, lk = l >> 4;
  f32x4 acc[8];
#pragma unroll
  for (int nt = 0; nt < 8; nt++) {
    int n = nt * 16 + lr;
    float wt[6];
#pragma unroll
    for (int c = 0; c < 6; c++) wt[c] = qs_w1f[(size_t)n * 134 + 128 + c];
    float bias = qs_b1[n];
#pragma unroll
    for (int r = 0; r < 4; r++) {
      int pl = wave * 16 + lk * 4 + r;
      float a = bias;
#pragma unroll
      for (int c = 0; c < 6; c++) a += wt[c] * sigf[pl][c];
      acc[nt][r] = a;
    }
  }
#pragma unroll
  for (int ks = 0; ks < 4; ks++) {
    short8 a = *(const short8*)&qin[wave * 16 + lr][ks * 32 + lk * 8];
#pragma unroll
    for (int nt = 0; nt < 8; nt++) {
      short8 bv = *(const short8*)(qsW1p + (size_t)(nt * 16 + lr) * 128 + ks * 32 + lk * 8);
      acc[nt] = __builtin_amdgcn_mfma_f32_16x16x32_bf16(a, bv, acc[nt], 0, 0, 0);
    }
  }
#pragma unroll
  for (int nt = 0; nt < 8; nt++)
#pragma unroll
    for (int r = 0; r < 4; r++)
      hq[wave * 16 + lk * 4 + r][nt * 16 + lr] = f2bf(geluf(acc[nt][r]));
  __syncthreads();
#pragma unroll
  for (int nt = 0; nt < 8; nt++) {
    float bias = qs_b2[nt * 16 + lr];
    acc[nt] = (f32x4){bias, bias, bias, bias};
  }
#pragma unroll
  for (int ks = 0; ks < 4; ks++) {
    short8 a = *(const short8*)&hq[wave * 16 + lr][ks * 32 + lk * 8];
#pragma unroll
    for (int nt = 0; nt < 8; nt++) {
      short8 bv = *(const short8*)(qsW2p + (size_t)(nt * 16 + lr) * 128 + ks * 32 + lk * 8);
      acc[nt] = __builtin_amdgcn_mfma_f32_16x16x32_bf16(a, bv, acc[nt], 0, 0, 0);
    }
  }
#pragma unroll
  for (int nt = 0; nt < 8; nt++) {
    int n = nt * 16 + lr;
#pragma unroll
    for (int r = 0; r < 4; r++) {
      int p = n0 + wave * 16 + lk * 4 + r;
      query[((size_t)b * NPIX + p) * 128 + n] = acc[nt][r];
    }
  }
}

// ---------------- K8: pack weights to bf16 ----------------
__global__ __launch_bounds__(256) void k_pack(
    const float* __restrict__ val_w, const float* __restrict__ w_v,
    const float* __restrict__ b_v, const float* __restrict__ val_b,
    const float* __restrict__ off_w, const float* __restrict__ off_b,
    const float* __restrict__ aw_w, const float* __restrict__ aw_b,
    const float* __restrict__ out_w, const float* __restrict__ qs_w1,
    const float* __restrict__ qs_w2, const float* __restrict__ rh_w1,
    const float* __restrict__ w_q, const float* __restrict__ w_o,
    const float* __restrict__ rh_w2,
    unsigned short* __restrict__ wvv_bf, float* __restrict__ bvv,
    unsigned short* __restrict__ projW, float* __restrict__ projB,
    unsigned short* __restrict__ outW, unsigned short* __restrict__ qsW1p,
    unsigned short* __restrict__ qsW2p, unsigned short* __restrict__ rhW1p,
    unsigned short* __restrict__ wqp, unsigned short* __restrict__ woP,
    unsigned short* __restrict__ w2p) {
  int idx = blockIdx.x * 256 + threadIdx.x;
  if (idx < 16384) {
    int o = idx >> 7, c = idx & 127;
    float acc = 0.0f;
    for (int m = 0; m < 128; m++) acc += val_w[o * 128 + m] * w_v[m * 128 + c];
    wvv_bf[idx] = f2bf(acc);
  } else if (idx < 16512) {
    int o = idx - 16384;
    float acc = val_b[o];
    for (int m = 0; m < 128; m++) acc += val_w[o * 128 + m] * b_v[m];
    bvv[o] = acc;
  } else if (idx < 82048) {
    int j = idx - 16512;
    int r = j >> 7, c = j & 127;
    float w = (r < 320) ? off_w[r * 128 + c] : ((r < 480) ? aw_w[(r - 320) * 128 + c] : 0.0f);
    projW[j] = f2bf(w);
  } else if (idx < 82560) {
    int r = idx - 82048;
    projB[r] = (r < 320) ? off_b[r] : ((r < 480) ? aw_b[r - 320] : 0.0f);
  } else if (idx < 98944) {
    int j = idx - 82560;
    outW[j] = f2bf(out_w[j]);
  } else if (idx < 115328) {
    int j = idx - 98944;
    int r = j >> 7, c = j & 127;
    qsW1p[j] = f2bf(qs_w1[r * 134 + c]);
  } else if (idx < 131712) {
    int j = idx - 115328;
    qsW2p[j] = f2bf(qs_w2[j]);
  } else if (idx < 144000) {
    int j = idx - 131712;
    int r = j / 96, c = j - r * 96;
    rhW1p[j] = (c < 67) ? f2bf(rh_w1[r * 67 + c]) : 0;
  } else if (idx < 156288) {
    int j = idx - 144000;
    int r = j / 96, c = j - r * 96;
    wqp[j] = (c < 64) ? f2bf(w_q[r * 64 + c]) : 0;
  } else if (idx < 172672) {
    int j = idx - 156288;
    woP[j] = f2bf(w_o[j]);
  } else if (idx < 246400) {
    int j = idx - 172672;          // [kpos][o][c]
    int kpos = j >> 13;
    int rem = j & 8191;
    int o = rem >> 7, c = rem & 127;
    int ky = kpos / 3, kx = kpos - ky * 3;
    w2p[j] = f2bf(rh_w2[((size_t)(o * 128 + c) * 3 + ky) * 3 + kx]);
  }
}

// ---------------- K9: MFMA value projection ----------------
__global__ __launch_bounds__(256) void k_value(
    const float* __restrict__ bev, const unsigned short* __restrict__ wvv_bf,
    const float* __restrict__ bvv, unsigned short* __restrict__ v) {
  __shared__ float lds[128 * 66];
  int b = blockIdx.y;
  int p0 = blockIdx.x * 64;
  int tid = threadIdx.x;
  int npx = NBEV - p0; if (npx > 64) npx = 64;
  for (int i = tid; i < 128 * 64; i += 256) {
    int c = i >> 6, p = i & 63;
    lds[c * 66 + p] = (p < npx) ? bev[((size_t)b * 128 + c) * NBEV + p0 + p] : 0.0f;
  }
  __syncthreads();
  int wave = tid >> 6, l = tid & 63;
  int lr = l & 15, lk = l >> 4;
  int ploc = wave * 16 + lr;
  f32x4 acc[8];
#pragma unroll
  for (int nt = 0; nt < 8; nt++) {
    float bias = bvv[nt * 16 + lr];
    acc[nt] = (f32x4){bias, bias, bias, bias};
  }
#pragma unroll
  for (int ks = 0; ks < 4; ks++) {
    int k0 = ks * 32 + lk * 8;
    short8 a;
#pragma unroll
    for (int j = 0; j < 8; j++) a[j] = (short)f2bf(lds[(k0 + j) * 66 + ploc]);
#pragma unroll
    for (int nt = 0; nt < 8; nt++) {
      short8 bf = *(const short8*)(wvv_bf + (size_t)(nt * 16 + lr) * 128 + k0);
      acc[nt] = __builtin_amdgcn_mfma_f32_16x16x32_bf16(a, bf, acc[nt], 0, 0, 0);
    }
  }
#pragma unroll
  for (int nt = 0; nt < 8; nt++) {
    int n = nt * 16 + lr;
#pragma unroll
    for (int r = 0; r < 4; r++) {
      int p = p0 + wave * 16 + lk * 4 + r;
      if (p < NBEV) v[((size_t)b * NBEV + p) * 128 + n] = f2bf(acc[nt][r]);
    }
  }
}

// ---------------- K10: MFMA projection (query -> 512 outs, bf16) ----------------
__global__ __launch_bounds__(256) void k_proj(
    const float* __restrict__ query, const unsigned short* __restrict__ projW,
    const float* __restrict__ projB, unsigned short* __restrict__ proj) {
  int b = blockIdx.z;
  int wave = threadIdx.x >> 6, l = threadIdx.x & 63;
  int lr = l & 15, lk = l >> 4;
  int p0 = blockIdx.x * 64 + wave * 16;
  int n0 = blockIdx.y * 128;
  f32x4 acc[8];
#pragma unroll
  for (int nt = 0; nt < 8; nt++) {
    float bias = projB[n0 + nt * 16 + lr];
    acc[nt] = (f32x4){bias, bias, bias, bias};
  }
  const float* ap = query + ((size_t)b * NPIX + p0 + lr) * 128 + lk * 8;
#pragma unroll
  for (int ks = 0; ks < 4; ks++) {
    float4 a0 = *(const float4*)(ap + ks * 32);
    float4 a1 = *(const float4*)(ap + ks * 32 + 4);
    short8 a;
    a[0] = (short)f2bf(a0.x); a[1] = (short)f2bf(a0.y);
    a[2] = (short)f2bf(a0.z); a[3] = (short)f2bf(a0.w);
    a[4] = (short)f2bf(a1.x); a[5] = (short)f2bf(a1.y);
    a[6] = (short)f2bf(a1.z); a[7] = (short)f2bf(a1.w);
#pragma unroll
    for (int nt = 0; nt < 8; nt++) {
      short8 bf = *(const short8*)(projW + (size_t)(n0 + nt * 16 + lr) * 128 + ks * 32 + lk * 8);
      acc[nt] = __builtin_amdgcn_mfma_f32_16x16x32_bf16(a, bf, acc[nt], 0, 0, 0);
    }
  }
#pragma unroll
  for (int nt = 0; nt < 8; nt++) {
    int n = n0 + nt * 16 + lr;
#pragma unroll
    for (int r = 0; r < 4; r++) {
      int p = p0 + lk * 4 + r;
      proj[((size_t)b * NPIX + p) * 512 + n] = f2bf(acc[nt][r]);
    }
  }
}

// ---------------- K11: sampler ----------------
__global__ __launch_bounds__(256) void k_samp(
    const unsigned short* __restrict__ proj, const float* __restrict__ params,
    const unsigned short* __restrict__ v, unsigned short* __restrict__ S) {
  int b = blockIdx.y;
  int bid = blockIdx.x;
  int pb = (bid & 7) * 256 + (bid >> 3);
  int tid = threadIdx.x;
  int q = tid & 3, hh = (tid >> 2) & 7, pl = tid >> 5;
  int n = pb * 8 + pl;
  const unsigned short* base = proj + ((size_t)b * NPIX + n) * 512;
  float mx = -1e30f;
#pragma unroll
  for (int i = 0; i < 20; i++) mx = fmaxf(mx, bf2f(base[320 + hh * 20 + i]));
  float s = 0.0f;
#pragma unroll
  for (int i = 0; i < 20; i++) s += expf(bf2f(base[320 + hh * 20 + i]) - mx);
  float rs = 1.0f / s;
  const float* P = params + ((size_t)b * NPIX + n) * 16;
  const unsigned short* vb = v + (size_t)b * NBEV * 128 + hh * 16 + q * 4;
  float ac0 = 0.f, ac1 = 0.f, ac2 = 0.f, ac3 = 0.f;
  for (int kp = 0; kp < 20; kp++) {
    int k = kp >> 2, pp = kp & 3;
    float lx = P[3 + 2 * k] + bf2f(base[hh * 40 + k * 8 + pp * 2 + 0]) * (1.0f / 220.0f);
    float ly = P[4 + 2 * k] + bf2f(base[hh * 40 + k * 8 + pp * 2 + 1]) * (1.0f / 220.0f);
    float a = expf(bf2f(base[320 + hh * 20 + kp]) - mx) * rs;
    float X = lx * 220.0f - 0.5f;
    float Y = ly * 220.0f - 0.5f;
    float xf = floorf(X), yf = floorf(Y);
    float wx = X - xf, wy = Y - yf;
    int x0 = (int)xf, y0 = (int)yf;
#pragma unroll
    for (int dy = 0; dy < 2; dy++) {
      int yi = y0 + dy;
      if (yi < 0 || yi >= 220) continue;
      float wyv = dy ? wy : (1.0f - wy);
#pragma unroll
      for (int dx = 0; dx < 2; dx++) {
        int xi = x0 + dx;
        if (xi < 0 || xi >= 220) continue;
        float wgt = a * wyv * (dx ? wx : (1.0f - wx));
        uint2 raw = *(const uint2*)(vb + (size_t)(yi * 220 + xi) * 128);
        ac0 += wgt * bf2f((unsigned short)(raw.x & 0xffffu));
        ac1 += wgt * bf2f((unsigned short)(raw.x >> 16));
        ac2 += wgt * bf2f((unsigned short)(raw.y & 0xffffu));
        ac3 += wgt * bf2f((unsigned short)(raw.y >> 16));
      }
    }
  }
  uint2 outp;
  outp.x = (unsigned int)f2bf(ac0) | ((unsigned int)f2bf(ac1) << 16);
  outp.y = (unsigned int)f2bf(ac2) | ((unsigned int)f2bf(ac3) << 16);
  *(uint2*)(S + ((size_t)b * NPIX + n) * 128 + hh * 16 + q * 4) = outp;
}

// ---------------- K12: MFMA out-projection + residual ----------------
__global__ __launch_bounds__(256) void k_out(
    const unsigned short* __restrict__ S, const unsigned short* __restrict__ outW,
    const float* __restrict__ out_b, const float* __restrict__ query,
    float* __restrict__ ymsda) {
  int b = blockIdx.y;
  int wave = threadIdx.x >> 6, l = threadIdx.x & 63;
  int lr = l & 15, lk = l >> 4;
  int p0 = blockIdx.x * 64 + wave * 16;
  f32x4 acc[8];
#pragma unroll
  for (int nt = 0; nt < 8; nt++) {
    float bias = out_b[nt * 16 + lr];
    acc[nt] = (f32x4){bias, bias, bias, bias};
  }
  const unsigned short* ap = S + ((size_t)b * NPIX + p0 + lr) * 128 + lk * 8;
#pragma unroll
  for (int ks = 0; ks < 4; ks++) {
    short8 a = *(const short8*)(ap + ks * 32);
#pragma unroll
    for (int nt = 0; nt < 8; nt++) {
      short8 bf = *(const short8*)(outW + (size_t)(nt * 16 + lr) * 128 + ks * 32 + lk * 8);
      acc[nt] = __builtin_amdgcn_mfma_f32_16x16x32_bf16(a, bf, acc[nt], 0, 0, 0);
    }
  }
#pragma unroll
  for (int nt = 0; nt < 8; nt++) {
    int n = nt * 16 + lr;
#pragma unroll
    for (int r = 0; r < 4; r++) {
      int p = p0 + lk * 4 + r;
      size_t o = ((size_t)b * NPIX + p) * 128 + n;
      ymsda[o] = acc[nt][r] + query[o];
    }
  }
}

// ---------------- K13: MFMA final conv1x1 + transposed NCHW store ----------------
__global__ __launch_bounds__(256) void k_final(
    const float* __restrict__ ymsda, const unsigned short* __restrict__ woP,
    const float* __restrict__ b_o, float* __restrict__ out) {
  __shared__ float yt[128][67];
  int b = blockIdx.y;
  int p0 = blockIdx.x * 64;
  int tid = threadIdx.x;
  int wave = tid >> 6, l = tid & 63;
  int lr = l & 15, lk = l >> 4;
  f32x4 acc[8];
#pragma unroll
  for (int nt = 0; nt < 8; nt++) {
    float bias = b_o[nt * 16 + lr];
    acc[nt] = (f32x4){bias, bias, bias, bias};
  }
  const float* ap = ymsda + ((size_t)b * NPIX + p0 + wave * 16 + lr) * 128 + lk * 8;
#pragma unroll
  for (int ks = 0; ks < 4; ks++) {
    float4 a0 = *(const float4*)(ap + ks * 32);
    float4 a1 = *(const float4*)(ap + ks * 32 + 4);
    short8 a;
    a[0] = (short)f2bf(a0.x); a[1] = (short)f2bf(a0.y);
    a[2] = (short)f2bf(a0.z); a[3] = (short)f2bf(a0.w);
    a[4] = (short)f2bf(a1.x); a[5] = (short)f2bf(a1.y);
    a[6] = (short)f2bf(a1.z); a[7] = (short)f2bf(a1.w);
#pragma unroll
    for (int nt = 0; nt < 8; nt++) {
      short8 bf = *(const short8*)(woP + (size_t)(nt * 16 + lr) * 128 + ks * 32 + lk * 8);
      acc[nt] = __builtin_amdgcn_mfma_f32_16x16x32_bf16(a, bf, acc[nt], 0, 0, 0);
    }
  }
#pragma unroll
  for (int nt = 0; nt < 8; nt++)
#pragma unroll
    for (int r = 0; r < 4; r++)
      yt[nt * 16 + lr][wave * 16 + lk * 4 + r] = acc[nt][r];
  __syncthreads();
  int n = tid >> 1, half = tid & 1;
  float* dst = out + ((size_t)(b * 128 + n)) * NPIX + p0 + half * 32;
#pragma unroll
  for (int j = 0; j < 8; j++) {
    float4 v4 = {yt[n][half * 32 + j * 4], yt[n][half * 32 + j * 4 + 1],
                 yt[n][half * 32 + j * 4 + 2], yt[n][half * 32 + j * 4 + 3]};
    *(float4*)(dst + j * 4) = v4;
  }
}

__global__ void k_klfin(const float* __restrict__ klpart, float* __restrict__ out) {
  if (threadIdx.x == 0) {
    float s = 0.0f;
    for (int i = 0; i < 128; i++) s += klpart[i];
    out[(size_t)BSZ * 128 * NPIX] = 1e-4f * (s / 32768.0f);
  }
}

// ---------------- host ----------------
static RVConsts make_consts() {
  static const float ELEV[32] = {
      -30.67f, -29.33f, -28.0f, -26.66f, -25.33f, -24.0f, -22.67f, -21.33f,
      -20.0f,  -18.67f, -17.33f, -16.0f, -14.67f, -13.33f, -12.0f, -10.67f,
      -9.33f,  -8.0f,   -6.66f,  -5.33f, -4.0f,   -2.67f,  -1.33f, 0.0f,
      1.33f,   2.67f,   4.0f,    5.33f,  6.67f,   8.0f,    9.33f,  10.67f};
  RVConsts C;
  const float d2r = 0.017453292519943295f;
  for (int r = 0; r < 16; r++) {
    float a = ELEV[31 - 2 * r], b = ELEV[30 - 2 * r];
    float mx = fmaxf(a, b), mn = fminf(a, b);
    C.steps[r] = (mx - mn) * d2r;
    C.means[r] = ((a + b) * 0.5f) * d2r;
  }
  const double PI_D = 3.14159265358979323846;
  double step_d = (PI_D - (-PI_D)) / 1024.0;
  double az0 = -PI_D;
  double az1 = az0 + step_d;
  double az_step_d = az1 - az0;
  C.az_step_f = (float)az_step_d;
  C.pad_ = 0.0f;
  C.step_d = step_d;
  C.az0 = az0;
  C.az_half = az_step_d * 0.5;
  return C;
}

// Workspace layout (f32 words). Peak 21,620,608 words = 86.5 MB.
#define OFF_T1     0u
#define OFF_H1     4194304u    /* bf16 x 4,194,304 -> 2,097,152 w */
#define OFF_T2     8388608u
#define OFF_Q0     10485760u
#define OFF_PARAMS 14680064u
#define OFF_QUERY  15204352u
#define OFF_S      19398656u
#define OFF_SUMS1  21495808u
#define OFF_SUMS2  21496320u
#define OFF_STATS1 21496832u
#define OFF_STATS2 21496864u
#define OFF_KL     21496896u
#define OFF_PROJ   0u
#define OFF_V      8388608u
#define OFF_YMSDA  0u
#define OFF_WVV    21497088u
#define OFF_BVV    21505280u
#define OFF_PROJW  21505408u
#define OFF_PROJB  21538176u
#define OFF_OUTW   21538688u
#define OFF_QSW1   21546880u
#define OFF_QSW2   21555072u
#define OFF_RHW1   21563264u
#define OFF_WQP    21569408u
#define OFF_WOP    21575552u
#define OFF_W2P    21583744u   /* bf16 x 73728 -> 36864 w */

extern "C" void kernel_launch(void* const* d_in, const int* in_sizes, int n_in,
                              void* d_out, int out_size, void* d_ws, size_t ws_size,
                              hipStream_t stream) {
  const float* x_rv = (const float*)d_in[0];
  const float* bev = (const float*)d_in[1];
  const float* l2e = (const float*)d_in[2];
  const float* w_q = (const float*)d_in[3];
  const float* b_q = (const float*)d_in[4];
  const float* w_v = (const float*)d_in[5];
  const float* b_v = (const float*)d_in[6];
  const float* w_o = (const float*)d_in[7];
  const float* b_o = (const float*)d_in[8];
  const float* qs_w1 = (const float*)d_in[9];
  const float* qs_b1 = (const float*)d_in[10];
  const float* qs_w2 = (const float*)d_in[11];
  const float* qs_b2 = (const float*)d_in[12];
  const float* rh_w1 = (const float*)d_in[13];
  const float* rh_b1 = (const float*)d_in[14];
  const float* rh_g1 = (const float*)d_in[15];
  const float* rh_bt1 = (const float*)d_in[16];
  const float* rh_w2 = (const float*)d_in[17];
  const float* rh_g2 = (const float*)d_in[18];
  const float* rh_bt2 = (const float*)d_in[19];
  const float* rh_w3 = (const float*)d_in[20];
  const float* rh_b3 = (const float*)d_in[21];
  const float* off_w = (const float*)d_in[22];
  const float* off_b = (const float*)d_in[23];
  const float* aw_w = (const float*)d_in[24];
  const float* aw_b = (const float*)d_in[25];
  const float* val_w = (const float*)d_in[26];
  const float* val_b = (const float*)d_in[27];
  const float* out_w = (const float*)d_in[28];
  const float* out_b = (const float*)d_in[29];

  float* ws = (float*)d_ws;
  float* t1 = ws + OFF_T1;
  float* t2 = ws + OFF_T2;
  float* q0 = ws + OFF_Q0;
  float* params = ws + OFF_PARAMS;
  float* query = ws + OFF_QUERY;
  float* sums1 = ws + OFF_SUMS1;
  float* sums2 = ws + OFF_SUMS2;
  float* stats1 = ws + OFF_STATS1;
  float* stats2 = ws + OFF_STATS2;
  float* klpart = ws + OFF_KL;
  float* bvv = ws + OFF_BVV;
  float* projB = ws + OFF_PROJB;
  float* ymsda = ws + OFF_YMSDA;
  unsigned short* h1bf = (unsigned short*)(ws + OFF_H1);
  unsigned short* S_bf = (unsigned short*)(ws + OFF_S);
  unsigned short* proj_bf = (unsigned short*)(ws + OFF_PROJ);
  unsigned short* v_bf = (unsigned short*)(ws + OFF_V);
  unsigned short* wvv_bf = (unsigned short*)(ws + OFF_WVV);
  unsigned short* projW = (unsigned short*)(ws + OFF_PROJW);
  unsigned short* outW = (unsigned short*)(ws + OFF_OUTW);
  unsigned short* qsW1p = (unsigned short*)(ws + OFF_QSW1);
  unsigned short* qsW2p = (unsigned short*)(ws + OFF_QSW2);
  unsigned short* rhW1p = (unsigned short*)(ws + OFF_RHW1);
  unsigned short* wqp = (unsigned short*)(ws + OFF_WQP);
  unsigned short* woP = (unsigned short*)(ws + OFF_WOP);
  unsigned short* w2p = (unsigned short*)(ws + OFF_W2P);

  RVConsts C = make_consts();
  dim3 blk(256);

  k_pack<<<963, blk, 0, stream>>>(val_w, w_v, b_v, val_b, off_w, off_b, aw_w, aw_b, out_w,
                                  qs_w1, qs_w2, rh_w1, w_q, w_o, rh_w2,
                                  wvv_bf, bvv, projW, projB, outW, qsW1p, qsW2p, rhW1p,
                                  wqp, woP, w2p);
  k_rh1_q0<<<dim3(256, BSZ), blk, 0, stream>>>(x_rv, rhW1p, rh_b1, wqp, b_q, t1, q0, C);
  k_gnsum<128, 16><<<dim3(16, 8, BSZ), blk, 0, stream>>>(t1, sums1);
  k_gnfin<<<1, 64, 0, stream>>>(sums1, stats1, 1.0f / 262144.0f);
  k_gn1_gelu<<<4096, blk, 0, stream>>>(t1, stats1, rh_g1, rh_bt1, h1bf);
  k_conv3<<<dim3(256, BSZ), blk, 0, stream>>>(h1bf, w2p, t2);
  k_gnsum<64, 8><<<dim3(16, 8, BSZ), blk, 0, stream>>>(t2, sums2);
  k_gnfin<<<1, 64, 0, stream>>>(sums2, stats2, 1.0f / 131072.0f);
  k_head<<<dim3(64, BSZ), blk, 0, stream>>>(t2, stats2, rh_g2, rh_bt2, rh_w3, rh_b3,
                                            l2e, params, klpart, C);
  k_query<<<dim3(256, BSZ), blk, 0, stream>>>(q0, params, qsW1p, qs_b1, qs_w1, qsW2p,
                                              qs_b2, query);
  k_value<<<dim3(757, BSZ), blk, 0, stream>>>(bev, wvv_bf, bvv, v_bf);
  k_proj<<<dim3(256, 4, BSZ), blk, 0, stream>>>(query, projW, projB, proj_bf);
  k_samp<<<dim3(2048, BSZ), blk, 0, stream>>>(proj_bf, params, v_bf, S_bf);
  k_out<<<dim3(256, BSZ), blk, 0, stream>>>(S_bf, outW, out_b, query, ymsda);
  k_final<<<dim3(256, BSZ), blk, 0, stream>>>(ymsda, woP, b_o, (float*)d_out);
  k_klfin<<<1, 64, 0, stream>>>(klpart, (float*)d_out);
}